// Round 1
// baseline (1045.174 us; speedup 1.0000x reference)
//
#include <hip/hip_runtime.h>

#define N_NODES 100000
#define N_EDGES 1600000
#define D 128

#define BM 128
#define KC 32
#define APAD 4          // As row stride = BM + APAD = 132 floats -> 16B-aligned b128 reads

// ---------------- CSR build ----------------

__global__ __launch_bounds__(256) void hist_kernel(const int* __restrict__ dst,
                                                   int* __restrict__ deg) {
    int i = blockIdx.x * 256 + threadIdx.x;
    if (i < N_EDGES) atomicAdd(&deg[dst[i]], 1);
}

#define SCAN_T 1024
__global__ __launch_bounds__(SCAN_T) void scan_kernel(const int* __restrict__ deg,
                                                      int* __restrict__ row_ptr,
                                                      int* __restrict__ cursor,
                                                      float* __restrict__ deg_inv) {
    __shared__ int sums[SCAN_T];
    int tid = threadIdx.x;
    const int CH = (N_NODES + SCAN_T - 1) / SCAN_T;   // 98
    int base = tid * CH;
    int s = 0;
    for (int i = 0; i < CH; ++i) {
        int idx = base + i;
        if (idx < N_NODES) s += deg[idx];
    }
    sums[tid] = s;
    __syncthreads();
    for (int off = 1; off < SCAN_T; off <<= 1) {
        int v = (tid >= off) ? sums[tid - off] : 0;
        __syncthreads();
        sums[tid] += v;
        __syncthreads();
    }
    int run = sums[tid] - s;   // exclusive base for this thread's chunk
    for (int i = 0; i < CH; ++i) {
        int idx = base + i;
        if (idx < N_NODES) {
            int dv = deg[idx];
            row_ptr[idx] = run;
            cursor[idx]  = run;
            deg_inv[idx] = dv > 0 ? 1.0f / (float)dv : 0.0f;
            run += dv;
        }
    }
    if (tid == SCAN_T - 1) row_ptr[N_NODES] = sums[tid];
}

__global__ __launch_bounds__(256) void scatter_kernel(const int* __restrict__ src,
                                                      const int* __restrict__ dst,
                                                      const float* __restrict__ w1,
                                                      const float* __restrict__ w2,
                                                      int* __restrict__ cursor,
                                                      int* __restrict__ srcs,
                                                      float* __restrict__ w1s,
                                                      float* __restrict__ w2s) {
    int i = blockIdx.x * 256 + threadIdx.x;
    if (i < N_EDGES) {
        int d = dst[i];
        int p = atomicAdd(&cursor[d], 1);
        srcs[p] = src[i];
        w1s[p] = w1[i];
        w2s[p] = w2[i];
    }
}

// ---------------- SpMM (CSR gather, mean + leaky-relu) ----------------

__global__ __launch_bounds__(128) void spmm_kernel(const float* __restrict__ xin,
                                                   const int* __restrict__ srcs,
                                                   const float* __restrict__ ws,
                                                   const int* __restrict__ row_ptr,
                                                   const float* __restrict__ deg_inv,
                                                   float* __restrict__ out) {
    int n = blockIdx.x;
    int d = threadIdx.x;
    int beg = row_ptr[n], end = row_ptr[n + 1];
    float acc = 0.f;
    for (int i = beg; i < end; ++i) {
        int s = srcs[i];
        float w = ws[i];
        acc += w * xin[(long)s * D + d];
    }
    float a = acc * deg_inv[n];
    a = a > 0.f ? a : 0.01f * a;
    out[(long)n * D + d] = a;
}

// ---------------- Fused dual GEMM: out = relu([in1|in2] @ W + b) ----------------
// W: [256][128], tile BM=128 rows x 128 cols, 256 threads, 8x8 per-thread tile.

__global__ __launch_bounds__(256) void gemm_dual_kernel(const float* __restrict__ in1,
                                                        const float* __restrict__ in2,
                                                        const float* __restrict__ W,
                                                        const float* __restrict__ bias,
                                                        float* __restrict__ out) {
    __shared__ float As[KC][BM + APAD];
    __shared__ float Ws[KC][D];
    int tid = threadIdx.x;
    int tc = tid & 15;       // 16 col groups
    int tr = tid >> 4;       // 16 row groups
    int c0 = tc * 8;
    int r0g = blockIdx.x * BM;

    float acc[8][8];
#pragma unroll
    for (int j = 0; j < 8; ++j)
#pragma unroll
        for (int i = 0; i < 8; ++i) acc[j][i] = 0.f;

    for (int ch = 0; ch < 8; ++ch) {
        const float* src = (ch < 4) ? in1 : in2;
        int kb  = (ch & 3) * KC;   // col offset within source
        int wkb = ch * KC;         // row offset within W

        // stage A transposed: As[k][row]
        {
            int kk4  = (tid & 7) * 4;
            int rown = tid >> 3;    // 0..31
#pragma unroll
            for (int it = 0; it < 4; ++it) {
                int row = rown + it * 32;
                int gr = r0g + row;
                if (gr >= N_NODES) gr = N_NODES - 1;
                const float4 v = *reinterpret_cast<const float4*>(&src[(long)gr * D + kb + kk4]);
                As[kk4 + 0][row] = v.x;
                As[kk4 + 1][row] = v.y;
                As[kk4 + 2][row] = v.z;
                As[kk4 + 3][row] = v.w;
            }
        }
        // stage W
        {
            int c4  = (tid & 31) * 4;
            int kk0 = tid >> 5;     // 0..7
#pragma unroll
            for (int it = 0; it < 4; ++it) {
                int kk = kk0 + it * 8;
                *reinterpret_cast<float4*>(&Ws[kk][c4]) =
                    *reinterpret_cast<const float4*>(&W[(long)(wkb + kk) * D + c4]);
            }
        }
        __syncthreads();

#pragma unroll 8
        for (int kk = 0; kk < KC; ++kk) {
            float a[8], w[8];
#pragma unroll
            for (int j = 0; j < 8; ++j) a[j] = As[kk][tr * 8 + j];
#pragma unroll
            for (int i = 0; i < 8; ++i) w[i] = Ws[kk][c0 + i];
#pragma unroll
            for (int j = 0; j < 8; ++j)
#pragma unroll
                for (int i = 0; i < 8; ++i) acc[j][i] += a[j] * w[i];
        }
        __syncthreads();
    }

#pragma unroll
    for (int j = 0; j < 8; ++j) {
        int row = r0g + tr * 8 + j;
        if (row < N_NODES) {
#pragma unroll
            for (int i = 0; i < 8; ++i) {
                float v = acc[j][i] + bias[c0 + i];
                v = v > 0.f ? v : 0.f;
                out[(long)row * D + c0 + i] = v;
            }
        }
    }
}

// ---------------- Classifier: out = relu(H @ Wl1 + bl1) @ Wl2 + bl2 ----------------

__global__ __launch_bounds__(256) void cls_kernel(const float* __restrict__ H,
                                                  const float* __restrict__ Wl1,
                                                  const float* __restrict__ bl1,
                                                  const float* __restrict__ Wl2,
                                                  const float* __restrict__ bl2,
                                                  float* __restrict__ out) {
    __shared__ float As[KC][BM + APAD];
    __shared__ float Ws[KC][D];
    __shared__ float red[BM][2][16];
    int tid = threadIdx.x;
    int tc = tid & 15;
    int tr = tid >> 4;
    int c0 = tc * 8;
    int r0g = blockIdx.x * BM;

    float acc[8][8];
#pragma unroll
    for (int j = 0; j < 8; ++j)
#pragma unroll
        for (int i = 0; i < 8; ++i) acc[j][i] = 0.f;

    for (int ch = 0; ch < 4; ++ch) {
        int kb = ch * KC;
        {
            int kk4  = (tid & 7) * 4;
            int rown = tid >> 3;
#pragma unroll
            for (int it = 0; it < 4; ++it) {
                int row = rown + it * 32;
                int gr = r0g + row;
                if (gr >= N_NODES) gr = N_NODES - 1;
                const float4 v = *reinterpret_cast<const float4*>(&H[(long)gr * D + kb + kk4]);
                As[kk4 + 0][row] = v.x;
                As[kk4 + 1][row] = v.y;
                As[kk4 + 2][row] = v.z;
                As[kk4 + 3][row] = v.w;
            }
        }
        {
            int c4  = (tid & 31) * 4;
            int kk0 = tid >> 5;
#pragma unroll
            for (int it = 0; it < 4; ++it) {
                int kk = kk0 + it * 8;
                *reinterpret_cast<float4*>(&Ws[kk][c4]) =
                    *reinterpret_cast<const float4*>(&Wl1[(long)(kb + kk) * D + c4]);
            }
        }
        __syncthreads();

#pragma unroll 8
        for (int kk = 0; kk < KC; ++kk) {
            float a[8], w[8];
#pragma unroll
            for (int j = 0; j < 8; ++j) a[j] = As[kk][tr * 8 + j];
#pragma unroll
            for (int i = 0; i < 8; ++i) w[i] = Ws[kk][c0 + i];
#pragma unroll
            for (int j = 0; j < 8; ++j)
#pragma unroll
                for (int i = 0; i < 8; ++i) acc[j][i] += a[j] * w[i];
        }
        __syncthreads();
    }

    // epilogue: t = relu(acc + bl1), partial dot with Wl2 columns
    float w20[8], w21[8];
#pragma unroll
    for (int i = 0; i < 8; ++i) {
        w20[i] = Wl2[(c0 + i) * 2 + 0];
        w21[i] = Wl2[(c0 + i) * 2 + 1];
    }
#pragma unroll
    for (int j = 0; j < 8; ++j) {
        float p0 = 0.f, p1 = 0.f;
#pragma unroll
        for (int i = 0; i < 8; ++i) {
            float t = acc[j][i] + bl1[c0 + i];
            t = t > 0.f ? t : 0.f;
            p0 += t * w20[i];
            p1 += t * w21[i];
        }
        red[tr * 8 + j][0][tc] = p0;
        red[tr * 8 + j][1][tc] = p1;
    }
    __syncthreads();
    {
        int rl = tid >> 1, m = tid & 1;
        float s = bl2[m];
#pragma unroll
        for (int t = 0; t < 16; ++t) s += red[rl][m][t];
        int grow = r0g + rl;
        if (grow < N_NODES) out[(long)grow * 2 + m] = s;
    }
}

// ---------------- launch ----------------

extern "C" void kernel_launch(void* const* d_in, const int* in_sizes, int n_in,
                              void* d_out, int out_size, void* d_ws, size_t ws_size,
                              hipStream_t stream) {
    const float* x   = (const float*)d_in[0];
    const int* esrc  = (const int*)d_in[1];
    const int* edst  = (const int*)d_in[2];
    const float* ew1 = (const float*)d_in[3];
    const float* ew2 = (const float*)d_in[4];
    const float* W1  = (const float*)d_in[5];
    const float* b1  = (const float*)d_in[6];
    const float* W2  = (const float*)d_in[7];
    const float* b2  = (const float*)d_in[8];
    const float* Wl1 = (const float*)d_in[9];
    const float* bl1 = (const float*)d_in[10];
    const float* Wl2 = (const float*)d_in[11];
    const float* bl2 = (const float*)d_in[12];
    float* out = (float*)d_out;

    char* p = (char*)d_ws;
    float* A       = (float*)p;            p += (size_t)N_NODES * D * 4;   // agg / h2
    float* B       = (float*)p;            p += (size_t)N_NODES * D * 4;   // h1
    float* deg_inv = (float*)p;            p += (size_t)N_NODES * 4;
    int* deg       = (int*)p;              p += (size_t)N_NODES * 4;
    int* row_ptr   = (int*)p;              p += (size_t)(N_NODES + 1) * 4;
    int* cursor    = (int*)p;              p += (size_t)N_NODES * 4;
    int* srcs      = (int*)p;              p += (size_t)N_EDGES * 4;
    float* w1s     = (float*)p;            p += (size_t)N_EDGES * 4;
    float* w2s     = (float*)p;            p += (size_t)N_EDGES * 4;

    hipMemsetAsync(deg, 0, (size_t)N_NODES * 4, stream);

    int egrid = (N_EDGES + 255) / 256;
    hist_kernel<<<egrid, 256, 0, stream>>>(edst, deg);
    scan_kernel<<<1, SCAN_T, 0, stream>>>(deg, row_ptr, cursor, deg_inv);
    scatter_kernel<<<egrid, 256, 0, stream>>>(esrc, edst, ew1, ew2, cursor, srcs, w1s, w2s);

    int ggrid = (N_NODES + BM - 1) / BM;   // 782

    // layer 1
    spmm_kernel<<<N_NODES, 128, 0, stream>>>(x, srcs, w1s, row_ptr, deg_inv, A);
    gemm_dual_kernel<<<ggrid, 256, 0, stream>>>(x, A, W1, b1, B);
    // layer 2
    spmm_kernel<<<N_NODES, 128, 0, stream>>>(B, srcs, w2s, row_ptr, deg_inv, A);
    gemm_dual_kernel<<<ggrid, 256, 0, stream>>>(B, A, W2, b2, A);   // h2 overwrites A (row-disjoint, reads precede writes)
    // classifier
    cls_kernel<<<ggrid, 256, 0, stream>>>(A, Wl1, bl1, Wl2, bl2, out);
}

// Round 2
// 651.105 us; speedup vs baseline: 1.6052x; 1.6052x over previous
//
#include <hip/hip_runtime.h>

#define N_NODES 100000
#define N_EDGES 1600000
#define D 128

#define BM 128
#define KC 32
#define APAD 4          // As row stride = BM + APAD = 132 floats -> 16B-aligned b128 reads

// ---------------- CSR build ----------------

__global__ __launch_bounds__(256) void hist_kernel(const int* __restrict__ dst,
                                                   int* __restrict__ deg) {
    int i = blockIdx.x * 256 + threadIdx.x;
    if (i < N_EDGES) atomicAdd(&deg[dst[i]], 1);
}

// ---- hierarchical scan: S1 block-reduce, S2 scan partials, S3 local scan + offset ----
#define SCAN_BLK 1024
#define SCAN_THR 256
#define SCAN_NBLK ((N_NODES + SCAN_BLK - 1) / SCAN_BLK)   // 98

__global__ __launch_bounds__(SCAN_THR) void scan1_kernel(const int* __restrict__ deg,
                                                         int* __restrict__ blocksums) {
    __shared__ int sums[SCAN_THR];
    int tid = threadIdx.x;
    int base = blockIdx.x * SCAN_BLK + tid * 4;
    int s = 0;
    if (base + 3 < N_NODES) {
        const int4 v = *reinterpret_cast<const int4*>(&deg[base]);
        s = v.x + v.y + v.z + v.w;
    } else {
#pragma unroll
        for (int i = 0; i < 4; ++i)
            if (base + i < N_NODES) s += deg[base + i];
    }
    sums[tid] = s;
    __syncthreads();
#pragma unroll
    for (int off = SCAN_THR / 2; off > 0; off >>= 1) {
        if (tid < off) sums[tid] += sums[tid + off];
        __syncthreads();
    }
    if (tid == 0) blocksums[blockIdx.x] = sums[0];
}

__global__ __launch_bounds__(128) void scan2_kernel(const int* __restrict__ blocksums,
                                                    int* __restrict__ blockoff,
                                                    int* __restrict__ row_ptr) {
    __shared__ int s[128];
    int tid = threadIdx.x;
    int v = (tid < SCAN_NBLK) ? blocksums[tid] : 0;
    s[tid] = v;
    __syncthreads();
    for (int off = 1; off < 128; off <<= 1) {
        int t = (tid >= off) ? s[tid - off] : 0;
        __syncthreads();
        s[tid] += t;
        __syncthreads();
    }
    if (tid < SCAN_NBLK) blockoff[tid] = s[tid] - v;   // exclusive
    if (tid == 127) row_ptr[N_NODES] = s[127];         // grand total
}

__global__ __launch_bounds__(SCAN_THR) void scan3_kernel(const int* __restrict__ deg,
                                                         const int* __restrict__ blockoff,
                                                         int* __restrict__ row_ptr,
                                                         int* __restrict__ cursor,
                                                         float* __restrict__ deg_inv) {
    __shared__ int tsum[SCAN_THR];
    int tid = threadIdx.x;
    int base = blockIdx.x * SCAN_BLK + tid * 4;
    int d[4];
#pragma unroll
    for (int i = 0; i < 4; ++i)
        d[i] = (base + i < N_NODES) ? deg[base + i] : 0;
    int s = d[0] + d[1] + d[2] + d[3];
    tsum[tid] = s;
    __syncthreads();
    for (int off = 1; off < SCAN_THR; off <<= 1) {
        int t = (tid >= off) ? tsum[tid - off] : 0;
        __syncthreads();
        tsum[tid] += t;
        __syncthreads();
    }
    int run = blockoff[blockIdx.x] + tsum[tid] - s;    // exclusive start
#pragma unroll
    for (int i = 0; i < 4; ++i) {
        int idx = base + i;
        if (idx < N_NODES) {
            row_ptr[idx] = run;
            cursor[idx]  = run;
            deg_inv[idx] = d[i] > 0 ? 1.0f / (float)d[i] : 0.0f;
            run += d[i];
        }
    }
}

__global__ __launch_bounds__(256) void scatter_kernel(const int* __restrict__ src,
                                                      const int* __restrict__ dst,
                                                      const float* __restrict__ w1,
                                                      const float* __restrict__ w2,
                                                      int* __restrict__ cursor,
                                                      int* __restrict__ srcs,
                                                      float* __restrict__ w1s,
                                                      float* __restrict__ w2s) {
    int i = blockIdx.x * 256 + threadIdx.x;
    if (i < N_EDGES) {
        int d = dst[i];
        int p = atomicAdd(&cursor[d], 1);
        srcs[p] = src[i];
        w1s[p] = w1[i];
        w2s[p] = w2[i];
    }
}

// ---------------- SpMM (CSR gather, mean + leaky-relu) ----------------
// wave-per-node: 256 threads = 4 waves = 4 nodes; lane holds 2 dims (float2).

__global__ __launch_bounds__(256) void spmm_kernel(const float* __restrict__ xin,
                                                   const int* __restrict__ srcs,
                                                   const float* __restrict__ ws,
                                                   const int* __restrict__ row_ptr,
                                                   const float* __restrict__ deg_inv,
                                                   float* __restrict__ out) {
    int wid = threadIdx.x >> 6;
    int lane = threadIdx.x & 63;
    int n = blockIdx.x * 4 + wid;          // grid covers exactly N_NODES
    int beg = row_ptr[n], end = row_ptr[n + 1];
    float ax = 0.f, ay = 0.f;
    int i = beg;
    for (; i + 1 < end; i += 2) {
        int s0 = srcs[i], s1 = srcs[i + 1];
        float w0 = ws[i], w1 = ws[i + 1];
        const float2 v0 = *reinterpret_cast<const float2*>(&xin[(long)s0 * D + lane * 2]);
        const float2 v1 = *reinterpret_cast<const float2*>(&xin[(long)s1 * D + lane * 2]);
        ax += w0 * v0.x + w1 * v1.x;
        ay += w0 * v0.y + w1 * v1.y;
    }
    if (i < end) {
        int s0 = srcs[i];
        float w0 = ws[i];
        const float2 v0 = *reinterpret_cast<const float2*>(&xin[(long)s0 * D + lane * 2]);
        ax += w0 * v0.x;
        ay += w0 * v0.y;
    }
    float di = deg_inv[n];
    ax *= di; ay *= di;
    ax = ax > 0.f ? ax : 0.01f * ax;
    ay = ay > 0.f ? ay : 0.01f * ay;
    float2 r; r.x = ax; r.y = ay;
    *reinterpret_cast<float2*>(&out[(long)n * D + lane * 2]) = r;
}

// ---------------- Fused dual GEMM: out = relu([in1|in2] @ W + b) ----------------

__global__ __launch_bounds__(256) void gemm_dual_kernel(const float* __restrict__ in1,
                                                        const float* __restrict__ in2,
                                                        const float* __restrict__ W,
                                                        const float* __restrict__ bias,
                                                        float* __restrict__ out) {
    __shared__ float As[KC][BM + APAD];
    __shared__ float Ws[KC][D];
    int tid = threadIdx.x;
    int tc = tid & 15;       // 16 col groups
    int tr = tid >> 4;       // 16 row groups
    int c0 = tc * 8;
    int r0g = blockIdx.x * BM;

    float acc[8][8];
#pragma unroll
    for (int j = 0; j < 8; ++j)
#pragma unroll
        for (int i = 0; i < 8; ++i) acc[j][i] = 0.f;

    for (int ch = 0; ch < 8; ++ch) {
        const float* src = (ch < 4) ? in1 : in2;
        int kb  = (ch & 3) * KC;   // col offset within source
        int wkb = ch * KC;         // row offset within W

        // stage A transposed: As[k][row]
        {
            int kk4  = (tid & 7) * 4;
            int rown = tid >> 3;    // 0..31
#pragma unroll
            for (int it = 0; it < 4; ++it) {
                int row = rown + it * 32;
                int gr = r0g + row;
                if (gr >= N_NODES) gr = N_NODES - 1;
                const float4 v = *reinterpret_cast<const float4*>(&src[(long)gr * D + kb + kk4]);
                As[kk4 + 0][row] = v.x;
                As[kk4 + 1][row] = v.y;
                As[kk4 + 2][row] = v.z;
                As[kk4 + 3][row] = v.w;
            }
        }
        // stage W
        {
            int c4  = (tid & 31) * 4;
            int kk0 = tid >> 5;     // 0..7
#pragma unroll
            for (int it = 0; it < 4; ++it) {
                int kk = kk0 + it * 8;
                *reinterpret_cast<float4*>(&Ws[kk][c4]) =
                    *reinterpret_cast<const float4*>(&W[(long)(wkb + kk) * D + c4]);
            }
        }
        __syncthreads();

#pragma unroll 8
        for (int kk = 0; kk < KC; ++kk) {
            float a[8], w[8];
#pragma unroll
            for (int j = 0; j < 8; ++j) a[j] = As[kk][tr * 8 + j];
#pragma unroll
            for (int i = 0; i < 8; ++i) w[i] = Ws[kk][c0 + i];
#pragma unroll
            for (int j = 0; j < 8; ++j)
#pragma unroll
                for (int i = 0; i < 8; ++i) acc[j][i] += a[j] * w[i];
        }
        __syncthreads();
    }

#pragma unroll
    for (int j = 0; j < 8; ++j) {
        int row = r0g + tr * 8 + j;
        if (row < N_NODES) {
#pragma unroll
            for (int i = 0; i < 8; ++i) {
                float v = acc[j][i] + bias[c0 + i];
                v = v > 0.f ? v : 0.f;
                out[(long)row * D + c0 + i] = v;
            }
        }
    }
}

// ---------------- Classifier: out = relu(H @ Wl1 + bl1) @ Wl2 + bl2 ----------------

__global__ __launch_bounds__(256) void cls_kernel(const float* __restrict__ H,
                                                  const float* __restrict__ Wl1,
                                                  const float* __restrict__ bl1,
                                                  const float* __restrict__ Wl2,
                                                  const float* __restrict__ bl2,
                                                  float* __restrict__ out) {
    __shared__ float As[KC][BM + APAD];
    __shared__ float Ws[KC][D];
    __shared__ float red[BM][2][16];
    int tid = threadIdx.x;
    int tc = tid & 15;
    int tr = tid >> 4;
    int c0 = tc * 8;
    int r0g = blockIdx.x * BM;

    float acc[8][8];
#pragma unroll
    for (int j = 0; j < 8; ++j)
#pragma unroll
        for (int i = 0; i < 8; ++i) acc[j][i] = 0.f;

    for (int ch = 0; ch < 4; ++ch) {
        int kb = ch * KC;
        {
            int kk4  = (tid & 7) * 4;
            int rown = tid >> 3;
#pragma unroll
            for (int it = 0; it < 4; ++it) {
                int row = rown + it * 32;
                int gr = r0g + row;
                if (gr >= N_NODES) gr = N_NODES - 1;
                const float4 v = *reinterpret_cast<const float4*>(&H[(long)gr * D + kb + kk4]);
                As[kk4 + 0][row] = v.x;
                As[kk4 + 1][row] = v.y;
                As[kk4 + 2][row] = v.z;
                As[kk4 + 3][row] = v.w;
            }
        }
        {
            int c4  = (tid & 31) * 4;
            int kk0 = tid >> 5;
#pragma unroll
            for (int it = 0; it < 4; ++it) {
                int kk = kk0 + it * 8;
                *reinterpret_cast<float4*>(&Ws[kk][c4]) =
                    *reinterpret_cast<const float4*>(&Wl1[(long)(kb + kk) * D + c4]);
            }
        }
        __syncthreads();

#pragma unroll 8
        for (int kk = 0; kk < KC; ++kk) {
            float a[8], w[8];
#pragma unroll
            for (int j = 0; j < 8; ++j) a[j] = As[kk][tr * 8 + j];
#pragma unroll
            for (int i = 0; i < 8; ++i) w[i] = Ws[kk][c0 + i];
#pragma unroll
            for (int j = 0; j < 8; ++j)
#pragma unroll
                for (int i = 0; i < 8; ++i) acc[j][i] += a[j] * w[i];
        }
        __syncthreads();
    }

    // epilogue: t = relu(acc + bl1), partial dot with Wl2 columns
    float w20[8], w21[8];
#pragma unroll
    for (int i = 0; i < 8; ++i) {
        w20[i] = Wl2[(c0 + i) * 2 + 0];
        w21[i] = Wl2[(c0 + i) * 2 + 1];
    }
#pragma unroll
    for (int j = 0; j < 8; ++j) {
        float p0 = 0.f, p1 = 0.f;
#pragma unroll
        for (int i = 0; i < 8; ++i) {
            float t = acc[j][i] + bl1[c0 + i];
            t = t > 0.f ? t : 0.f;
            p0 += t * w20[i];
            p1 += t * w21[i];
        }
        red[tr * 8 + j][0][tc] = p0;
        red[tr * 8 + j][1][tc] = p1;
    }
    __syncthreads();
    {
        int rl = tid >> 1, m = tid & 1;
        float s = bl2[m];
#pragma unroll
        for (int t = 0; t < 16; ++t) s += red[rl][m][t];
        int grow = r0g + rl;
        if (grow < N_NODES) out[(long)grow * 2 + m] = s;
    }
}

// ---------------- launch ----------------

extern "C" void kernel_launch(void* const* d_in, const int* in_sizes, int n_in,
                              void* d_out, int out_size, void* d_ws, size_t ws_size,
                              hipStream_t stream) {
    const float* x   = (const float*)d_in[0];
    const int* esrc  = (const int*)d_in[1];
    const int* edst  = (const int*)d_in[2];
    const float* ew1 = (const float*)d_in[3];
    const float* ew2 = (const float*)d_in[4];
    const float* W1  = (const float*)d_in[5];
    const float* b1  = (const float*)d_in[6];
    const float* W2  = (const float*)d_in[7];
    const float* b2  = (const float*)d_in[8];
    const float* Wl1 = (const float*)d_in[9];
    const float* bl1 = (const float*)d_in[10];
    const float* Wl2 = (const float*)d_in[11];
    const float* bl2 = (const float*)d_in[12];
    float* out = (float*)d_out;

    char* p = (char*)d_ws;
    float* A        = (float*)p;           p += (size_t)N_NODES * D * 4;   // agg / h2
    float* B        = (float*)p;           p += (size_t)N_NODES * D * 4;   // h1
    float* deg_inv  = (float*)p;           p += (size_t)N_NODES * 4;
    int* deg        = (int*)p;             p += (size_t)N_NODES * 4;
    int* row_ptr    = (int*)p;             p += (size_t)(N_NODES + 1) * 4;
    int* cursor     = (int*)p;             p += (size_t)N_NODES * 4;
    int* blocksums  = (int*)p;             p += 128 * 4;
    int* blockoff   = (int*)p;             p += 128 * 4;
    int* srcs       = (int*)p;             p += (size_t)N_EDGES * 4;
    float* w1s      = (float*)p;           p += (size_t)N_EDGES * 4;
    float* w2s      = (float*)p;           p += (size_t)N_EDGES * 4;

    hipMemsetAsync(deg, 0, (size_t)N_NODES * 4, stream);

    int egrid = (N_EDGES + 255) / 256;
    hist_kernel<<<egrid, 256, 0, stream>>>(edst, deg);
    scan1_kernel<<<SCAN_NBLK, SCAN_THR, 0, stream>>>(deg, blocksums);
    scan2_kernel<<<1, 128, 0, stream>>>(blocksums, blockoff, row_ptr);
    scan3_kernel<<<SCAN_NBLK, SCAN_THR, 0, stream>>>(deg, blockoff, row_ptr, cursor, deg_inv);
    scatter_kernel<<<egrid, 256, 0, stream>>>(esrc, edst, ew1, ew2, cursor, srcs, w1s, w2s);

    int ggrid = (N_NODES + BM - 1) / BM;   // 782

    // layer 1
    spmm_kernel<<<N_NODES / 4, 256, 0, stream>>>(x, srcs, w1s, row_ptr, deg_inv, A);
    gemm_dual_kernel<<<ggrid, 256, 0, stream>>>(x, A, W1, b1, B);
    // layer 2
    spmm_kernel<<<N_NODES / 4, 256, 0, stream>>>(B, srcs, w2s, row_ptr, deg_inv, A);
    gemm_dual_kernel<<<ggrid, 256, 0, stream>>>(B, A, W2, b2, A);   // h2 overwrites A (row-disjoint, reads precede writes)
    // classifier
    cls_kernel<<<ggrid, 256, 0, stream>>>(A, Wl1, bl1, Wl2, bl2, out);
}

// Round 3
// 642.940 us; speedup vs baseline: 1.6256x; 1.0127x over previous
//
#include <hip/hip_runtime.h>

#define N_NODES 100000
#define N_EDGES 1600000
#define D 128

#define BM 128
#define KC 32
#define APAD 4          // As row stride = BM + APAD = 132 floats -> 16B-aligned b128 reads

// ---------------- CSR build ----------------

// histogram + per-edge rank within its dst row (the atomic does double duty)
__global__ __launch_bounds__(256) void hist_kernel(const int* __restrict__ dst,
                                                   int* __restrict__ deg,
                                                   int* __restrict__ rank) {
    int i = blockIdx.x * 256 + threadIdx.x;
    if (i < N_EDGES) rank[i] = atomicAdd(&deg[dst[i]], 1);
}

// ---- hierarchical scan: S1 block-reduce, S2 scan partials, S3 local scan + offset ----
#define SCAN_BLK 1024
#define SCAN_THR 256
#define SCAN_NBLK ((N_NODES + SCAN_BLK - 1) / SCAN_BLK)   // 98

__global__ __launch_bounds__(SCAN_THR) void scan1_kernel(const int* __restrict__ deg,
                                                         int* __restrict__ blocksums) {
    __shared__ int sums[SCAN_THR];
    int tid = threadIdx.x;
    int base = blockIdx.x * SCAN_BLK + tid * 4;
    int s = 0;
    if (base + 3 < N_NODES) {
        const int4 v = *reinterpret_cast<const int4*>(&deg[base]);
        s = v.x + v.y + v.z + v.w;
    } else {
#pragma unroll
        for (int i = 0; i < 4; ++i)
            if (base + i < N_NODES) s += deg[base + i];
    }
    sums[tid] = s;
    __syncthreads();
#pragma unroll
    for (int off = SCAN_THR / 2; off > 0; off >>= 1) {
        if (tid < off) sums[tid] += sums[tid + off];
        __syncthreads();
    }
    if (tid == 0) blocksums[blockIdx.x] = sums[0];
}

__global__ __launch_bounds__(128) void scan2_kernel(const int* __restrict__ blocksums,
                                                    int* __restrict__ blockoff,
                                                    int* __restrict__ row_ptr) {
    __shared__ int s[128];
    int tid = threadIdx.x;
    int v = (tid < SCAN_NBLK) ? blocksums[tid] : 0;
    s[tid] = v;
    __syncthreads();
    for (int off = 1; off < 128; off <<= 1) {
        int t = (tid >= off) ? s[tid - off] : 0;
        __syncthreads();
        s[tid] += t;
        __syncthreads();
    }
    if (tid < SCAN_NBLK) blockoff[tid] = s[tid] - v;   // exclusive
    if (tid == 127) row_ptr[N_NODES] = s[127];         // grand total
}

__global__ __launch_bounds__(SCAN_THR) void scan3_kernel(const int* __restrict__ deg,
                                                         const int* __restrict__ blockoff,
                                                         int* __restrict__ row_ptr,
                                                         float* __restrict__ deg_inv) {
    __shared__ int tsum[SCAN_THR];
    int tid = threadIdx.x;
    int base = blockIdx.x * SCAN_BLK + tid * 4;
    int d[4];
#pragma unroll
    for (int i = 0; i < 4; ++i)
        d[i] = (base + i < N_NODES) ? deg[base + i] : 0;
    int s = d[0] + d[1] + d[2] + d[3];
    tsum[tid] = s;
    __syncthreads();
    for (int off = 1; off < SCAN_THR; off <<= 1) {
        int t = (tid >= off) ? tsum[tid - off] : 0;
        __syncthreads();
        tsum[tid] += t;
        __syncthreads();
    }
    int run = blockoff[blockIdx.x] + tsum[tid] - s;    // exclusive start
#pragma unroll
    for (int i = 0; i < 4; ++i) {
        int idx = base + i;
        if (idx < N_NODES) {
            row_ptr[idx] = run;
            deg_inv[idx] = d[i] > 0 ? 1.0f / (float)d[i] : 0.0f;
            run += d[i];
        }
    }
}

// atomic-free scatter: one 16B packed write per edge
__global__ __launch_bounds__(256) void scatter_kernel(const int* __restrict__ src,
                                                      const int* __restrict__ dst,
                                                      const float* __restrict__ w1,
                                                      const float* __restrict__ w2,
                                                      const int* __restrict__ rank,
                                                      const int* __restrict__ row_ptr,
                                                      int4* __restrict__ packed) {
    int i = blockIdx.x * 256 + threadIdx.x;
    if (i < N_EDGES) {
        int d = dst[i];
        int p = row_ptr[d] + rank[i];
        int4 e;
        e.x = src[i];
        e.y = __float_as_int(w1[i]);
        e.z = __float_as_int(w2[i]);
        e.w = 0;
        packed[p] = e;
    }
}

// ---------------- SpMM (CSR gather, mean + leaky-relu) ----------------
// wave-per-node: 256 threads = 4 waves = 4 nodes; lane holds 2 dims (float2).

__global__ __launch_bounds__(256) void spmm_kernel(const float* __restrict__ xin,
                                                   const int4* __restrict__ edges,
                                                   const int* __restrict__ row_ptr,
                                                   const float* __restrict__ deg_inv,
                                                   float* __restrict__ out,
                                                   int widx) {
    int wid = threadIdx.x >> 6;
    int lane = threadIdx.x & 63;
    int n = blockIdx.x * 4 + wid;          // grid covers exactly N_NODES
    int beg = row_ptr[n], end = row_ptr[n + 1];
    float ax = 0.f, ay = 0.f;
    int i = beg;
    for (; i + 1 < end; i += 2) {
        const int4 e0 = edges[i];
        const int4 e1 = edges[i + 1];
        float w0 = __int_as_float(widx ? e0.z : e0.y);
        float w1 = __int_as_float(widx ? e1.z : e1.y);
        const float2 v0 = *reinterpret_cast<const float2*>(&xin[(long)e0.x * D + lane * 2]);
        const float2 v1 = *reinterpret_cast<const float2*>(&xin[(long)e1.x * D + lane * 2]);
        ax += w0 * v0.x + w1 * v1.x;
        ay += w0 * v0.y + w1 * v1.y;
    }
    if (i < end) {
        const int4 e0 = edges[i];
        float w0 = __int_as_float(widx ? e0.z : e0.y);
        const float2 v0 = *reinterpret_cast<const float2*>(&xin[(long)e0.x * D + lane * 2]);
        ax += w0 * v0.x;
        ay += w0 * v0.y;
    }
    float di = deg_inv[n];
    ax *= di; ay *= di;
    ax = ax > 0.f ? ax : 0.01f * ax;
    ay = ay > 0.f ? ay : 0.01f * ay;
    float2 r; r.x = ax; r.y = ay;
    *reinterpret_cast<float2*>(&out[(long)n * D + lane * 2]) = r;
}

// ---------------- Fused dual GEMM: out = relu([in1|in2] @ W + b) ----------------

__global__ __launch_bounds__(256) void gemm_dual_kernel(const float* __restrict__ in1,
                                                        const float* __restrict__ in2,
                                                        const float* __restrict__ W,
                                                        const float* __restrict__ bias,
                                                        float* __restrict__ out) {
    __shared__ float As[KC][BM + APAD];
    __shared__ float Ws[KC][D];
    int tid = threadIdx.x;
    int tc = tid & 15;       // 16 col groups
    int tr = tid >> 4;       // 16 row groups
    int c0 = tc * 8;
    int r0g = blockIdx.x * BM;

    float acc[8][8];
#pragma unroll
    for (int j = 0; j < 8; ++j)
#pragma unroll
        for (int i = 0; i < 8; ++i) acc[j][i] = 0.f;

    for (int ch = 0; ch < 8; ++ch) {
        const float* src = (ch < 4) ? in1 : in2;
        int kb  = (ch & 3) * KC;   // col offset within source
        int wkb = ch * KC;         // row offset within W

        // stage A transposed: As[k][row]
        {
            int kk4  = (tid & 7) * 4;
            int rown = tid >> 3;    // 0..31
#pragma unroll
            for (int it = 0; it < 4; ++it) {
                int row = rown + it * 32;
                int gr = r0g + row;
                if (gr >= N_NODES) gr = N_NODES - 1;
                const float4 v = *reinterpret_cast<const float4*>(&src[(long)gr * D + kb + kk4]);
                As[kk4 + 0][row] = v.x;
                As[kk4 + 1][row] = v.y;
                As[kk4 + 2][row] = v.z;
                As[kk4 + 3][row] = v.w;
            }
        }
        // stage W
        {
            int c4  = (tid & 31) * 4;
            int kk0 = tid >> 5;     // 0..7
#pragma unroll
            for (int it = 0; it < 4; ++it) {
                int kk = kk0 + it * 8;
                *reinterpret_cast<float4*>(&Ws[kk][c4]) =
                    *reinterpret_cast<const float4*>(&W[(long)(wkb + kk) * D + c4]);
            }
        }
        __syncthreads();

#pragma unroll 8
        for (int kk = 0; kk < KC; ++kk) {
            float a[8], w[8];
#pragma unroll
            for (int j = 0; j < 8; ++j) a[j] = As[kk][tr * 8 + j];
#pragma unroll
            for (int i = 0; i < 8; ++i) w[i] = Ws[kk][c0 + i];
#pragma unroll
            for (int j = 0; j < 8; ++j)
#pragma unroll
                for (int i = 0; i < 8; ++i) acc[j][i] += a[j] * w[i];
        }
        __syncthreads();
    }

#pragma unroll
    for (int j = 0; j < 8; ++j) {
        int row = r0g + tr * 8 + j;
        if (row < N_NODES) {
#pragma unroll
            for (int i = 0; i < 8; ++i) {
                float v = acc[j][i] + bias[c0 + i];
                v = v > 0.f ? v : 0.f;
                out[(long)row * D + c0 + i] = v;
            }
        }
    }
}

// ---------------- Classifier: out = relu(H @ Wl1 + bl1) @ Wl2 + bl2 ----------------

__global__ __launch_bounds__(256) void cls_kernel(const float* __restrict__ H,
                                                  const float* __restrict__ Wl1,
                                                  const float* __restrict__ bl1,
                                                  const float* __restrict__ Wl2,
                                                  const float* __restrict__ bl2,
                                                  float* __restrict__ out) {
    __shared__ float As[KC][BM + APAD];
    __shared__ float Ws[KC][D];
    __shared__ float red[BM][2][16];
    int tid = threadIdx.x;
    int tc = tid & 15;
    int tr = tid >> 4;
    int c0 = tc * 8;
    int r0g = blockIdx.x * BM;

    float acc[8][8];
#pragma unroll
    for (int j = 0; j < 8; ++j)
#pragma unroll
        for (int i = 0; i < 8; ++i) acc[j][i] = 0.f;

    for (int ch = 0; ch < 4; ++ch) {
        int kb = ch * KC;
        {
            int kk4  = (tid & 7) * 4;
            int rown = tid >> 3;
#pragma unroll
            for (int it = 0; it < 4; ++it) {
                int row = rown + it * 32;
                int gr = r0g + row;
                if (gr >= N_NODES) gr = N_NODES - 1;
                const float4 v = *reinterpret_cast<const float4*>(&H[(long)gr * D + kb + kk4]);
                As[kk4 + 0][row] = v.x;
                As[kk4 + 1][row] = v.y;
                As[kk4 + 2][row] = v.z;
                As[kk4 + 3][row] = v.w;
            }
        }
        {
            int c4  = (tid & 31) * 4;
            int kk0 = tid >> 5;
#pragma unroll
            for (int it = 0; it < 4; ++it) {
                int kk = kk0 + it * 8;
                *reinterpret_cast<float4*>(&Ws[kk][c4]) =
                    *reinterpret_cast<const float4*>(&Wl1[(long)(kb + kk) * D + c4]);
            }
        }
        __syncthreads();

#pragma unroll 8
        for (int kk = 0; kk < KC; ++kk) {
            float a[8], w[8];
#pragma unroll
            for (int j = 0; j < 8; ++j) a[j] = As[kk][tr * 8 + j];
#pragma unroll
            for (int i = 0; i < 8; ++i) w[i] = Ws[kk][c0 + i];
#pragma unroll
            for (int j = 0; j < 8; ++j)
#pragma unroll
                for (int i = 0; i < 8; ++i) acc[j][i] += a[j] * w[i];
        }
        __syncthreads();
    }

    // epilogue: t = relu(acc + bl1), partial dot with Wl2 columns
    float w20[8], w21[8];
#pragma unroll
    for (int i = 0; i < 8; ++i) {
        w20[i] = Wl2[(c0 + i) * 2 + 0];
        w21[i] = Wl2[(c0 + i) * 2 + 1];
    }
#pragma unroll
    for (int j = 0; j < 8; ++j) {
        float p0 = 0.f, p1 = 0.f;
#pragma unroll
        for (int i = 0; i < 8; ++i) {
            float t = acc[j][i] + bl1[c0 + i];
            t = t > 0.f ? t : 0.f;
            p0 += t * w20[i];
            p1 += t * w21[i];
        }
        red[tr * 8 + j][0][tc] = p0;
        red[tr * 8 + j][1][tc] = p1;
    }
    __syncthreads();
    {
        int rl = tid >> 1, m = tid & 1;
        float s = bl2[m];
#pragma unroll
        for (int t = 0; t < 16; ++t) s += red[rl][m][t];
        int grow = r0g + rl;
        if (grow < N_NODES) out[(long)grow * 2 + m] = s;
    }
}

// ---------------- launch ----------------

extern "C" void kernel_launch(void* const* d_in, const int* in_sizes, int n_in,
                              void* d_out, int out_size, void* d_ws, size_t ws_size,
                              hipStream_t stream) {
    const float* x   = (const float*)d_in[0];
    const int* esrc  = (const int*)d_in[1];
    const int* edst  = (const int*)d_in[2];
    const float* ew1 = (const float*)d_in[3];
    const float* ew2 = (const float*)d_in[4];
    const float* W1  = (const float*)d_in[5];
    const float* b1  = (const float*)d_in[6];
    const float* W2  = (const float*)d_in[7];
    const float* b2  = (const float*)d_in[8];
    const float* Wl1 = (const float*)d_in[9];
    const float* bl1 = (const float*)d_in[10];
    const float* Wl2 = (const float*)d_in[11];
    const float* bl2 = (const float*)d_in[12];
    float* out = (float*)d_out;

    char* p = (char*)d_ws;
    float* A        = (float*)p;           p += (size_t)N_NODES * D * 4;   // agg / h2
    float* B        = (float*)p;           p += (size_t)N_NODES * D * 4;   // h1
    float* deg_inv  = (float*)p;           p += (size_t)N_NODES * 4;
    int* deg        = (int*)p;             p += (size_t)N_NODES * 4;
    int* row_ptr    = (int*)p;             p += (size_t)(N_NODES + 1) * 4;
    int* blocksums  = (int*)p;             p += 128 * 4;
    int* blockoff   = (int*)p;             p += 128 * 4;
    int4* packed    = (int4*)p;            p += (size_t)N_EDGES * 16;
    int* rank       = (int*)B;             // aliases B (h1): dead before gemm1 writes B

    hipMemsetAsync(deg, 0, (size_t)N_NODES * 4, stream);

    int egrid = (N_EDGES + 255) / 256;
    hist_kernel<<<egrid, 256, 0, stream>>>(edst, deg, rank);
    scan1_kernel<<<SCAN_NBLK, SCAN_THR, 0, stream>>>(deg, blocksums);
    scan2_kernel<<<1, 128, 0, stream>>>(blocksums, blockoff, row_ptr);
    scan3_kernel<<<SCAN_NBLK, SCAN_THR, 0, stream>>>(deg, blockoff, row_ptr, deg_inv);
    scatter_kernel<<<egrid, 256, 0, stream>>>(esrc, edst, ew1, ew2, rank, row_ptr, packed);

    int ggrid = (N_NODES + BM - 1) / BM;   // 782

    // layer 1
    spmm_kernel<<<N_NODES / 4, 256, 0, stream>>>(x, packed, row_ptr, deg_inv, A, 0);
    gemm_dual_kernel<<<ggrid, 256, 0, stream>>>(x, A, W1, b1, B);
    // layer 2
    spmm_kernel<<<N_NODES / 4, 256, 0, stream>>>(B, packed, row_ptr, deg_inv, A, 1);
    gemm_dual_kernel<<<ggrid, 256, 0, stream>>>(B, A, W2, b2, A);   // h2 overwrites A (row-disjoint, reads precede writes)
    // classifier
    cls_kernel<<<ggrid, 256, 0, stream>>>(A, Wl1, bl1, Wl2, bl2, out);
}

// Round 4
// 570.136 us; speedup vs baseline: 1.8332x; 1.1277x over previous
//
#include <hip/hip_runtime.h>

#define N_NODES 100000
#define N_EDGES 1600000
#define D 128

#define BM 128
#define KC 32
#define APAD 4          // As row stride = BM + APAD = 132 floats -> 16B-aligned b128 reads

__device__ __forceinline__ ushort f2bf(float f) {
    unsigned u = __float_as_uint(f);
    u += 0x7FFFu + ((u >> 16) & 1u);   // RNE
    return (ushort)(u >> 16);
}
__device__ __forceinline__ float bf2f(ushort u) {
    return __uint_as_float(((unsigned)u) << 16);
}

// ---------------- CSR build ----------------

__global__ __launch_bounds__(256) void hist_kernel(const int* __restrict__ dst,
                                                   int* __restrict__ deg,
                                                   int* __restrict__ rank) {
    int i = blockIdx.x * 256 + threadIdx.x;
    if (i < N_EDGES) rank[i] = atomicAdd(&deg[dst[i]], 1);
}

#define SCAN_BLK 1024
#define SCAN_THR 256
#define SCAN_NBLK ((N_NODES + SCAN_BLK - 1) / SCAN_BLK)   // 98

__global__ __launch_bounds__(SCAN_THR) void scan1_kernel(const int* __restrict__ deg,
                                                         int* __restrict__ blocksums) {
    __shared__ int sums[SCAN_THR];
    int tid = threadIdx.x;
    int base = blockIdx.x * SCAN_BLK + tid * 4;
    int s = 0;
    if (base + 3 < N_NODES) {
        const int4 v = *reinterpret_cast<const int4*>(&deg[base]);
        s = v.x + v.y + v.z + v.w;
    } else {
#pragma unroll
        for (int i = 0; i < 4; ++i)
            if (base + i < N_NODES) s += deg[base + i];
    }
    sums[tid] = s;
    __syncthreads();
#pragma unroll
    for (int off = SCAN_THR / 2; off > 0; off >>= 1) {
        if (tid < off) sums[tid] += sums[tid + off];
        __syncthreads();
    }
    if (tid == 0) blocksums[blockIdx.x] = sums[0];
}

__global__ __launch_bounds__(128) void scan2_kernel(const int* __restrict__ blocksums,
                                                    int* __restrict__ blockoff,
                                                    int* __restrict__ row_ptr) {
    __shared__ int s[128];
    int tid = threadIdx.x;
    int v = (tid < SCAN_NBLK) ? blocksums[tid] : 0;
    s[tid] = v;
    __syncthreads();
    for (int off = 1; off < 128; off <<= 1) {
        int t = (tid >= off) ? s[tid - off] : 0;
        __syncthreads();
        s[tid] += t;
        __syncthreads();
    }
    if (tid < SCAN_NBLK) blockoff[tid] = s[tid] - v;   // exclusive
    if (tid == 127) row_ptr[N_NODES] = s[127];         // grand total
}

__global__ __launch_bounds__(SCAN_THR) void scan3_kernel(const int* __restrict__ deg,
                                                         const int* __restrict__ blockoff,
                                                         int* __restrict__ row_ptr,
                                                         float* __restrict__ deg_inv) {
    __shared__ int tsum[SCAN_THR];
    int tid = threadIdx.x;
    int base = blockIdx.x * SCAN_BLK + tid * 4;
    int d[4];
#pragma unroll
    for (int i = 0; i < 4; ++i)
        d[i] = (base + i < N_NODES) ? deg[base + i] : 0;
    int s = d[0] + d[1] + d[2] + d[3];
    tsum[tid] = s;
    __syncthreads();
    for (int off = 1; off < SCAN_THR; off <<= 1) {
        int t = (tid >= off) ? tsum[tid - off] : 0;
        __syncthreads();
        tsum[tid] += t;
        __syncthreads();
    }
    int run = blockoff[blockIdx.x] + tsum[tid] - s;    // exclusive start
#pragma unroll
    for (int i = 0; i < 4; ++i) {
        int idx = base + i;
        if (idx < N_NODES) {
            row_ptr[idx] = run;
            deg_inv[idx] = d[i] > 0 ? 1.0f / (float)d[i] : 0.0f;
            run += d[i];
        }
    }
}

// atomic-free scatter: one 16B packed write per edge
__global__ __launch_bounds__(256) void scatter_kernel(const int* __restrict__ src,
                                                      const int* __restrict__ dst,
                                                      const float* __restrict__ w1,
                                                      const float* __restrict__ w2,
                                                      const int* __restrict__ rank,
                                                      const int* __restrict__ row_ptr,
                                                      int4* __restrict__ packed) {
    int i = blockIdx.x * 256 + threadIdx.x;
    if (i < N_EDGES) {
        int d = dst[i];
        int p = row_ptr[d] + rank[i];
        int4 e;
        e.x = src[i];
        e.y = __float_as_int(w1[i]);
        e.z = __float_as_int(w2[i]);
        e.w = 0;
        packed[p] = e;
    }
}

// ---------------- fp32 -> bf16 convert (8 elems/thread) ----------------

__global__ __launch_bounds__(256) void cvt_bf16_kernel(const float* __restrict__ in,
                                                       ushort* __restrict__ out) {
    long i = ((long)blockIdx.x * 256 + threadIdx.x) * 8;   // total = N_NODES*D, divisible by 8
    const float4 a = *reinterpret_cast<const float4*>(&in[i]);
    const float4 b = *reinterpret_cast<const float4*>(&in[i + 4]);
    ushort4 u0, u1;
    u0.x = f2bf(a.x); u0.y = f2bf(a.y); u0.z = f2bf(a.z); u0.w = f2bf(a.w);
    u1.x = f2bf(b.x); u1.y = f2bf(b.y); u1.z = f2bf(b.z); u1.w = f2bf(b.w);
    *reinterpret_cast<ushort4*>(&out[i]) = u0;
    *reinterpret_cast<ushort4*>(&out[i + 4]) = u1;
}

// ---------------- SpMM (CSR gather of bf16 rows, fp32 accum, mean + leaky-relu) ----
// wave-per-node: 256 threads = 4 waves = 4 nodes; lane holds 2 dims (ushort2 load).

__global__ __launch_bounds__(256) void spmm_kernel(const ushort* __restrict__ xin,
                                                   const int4* __restrict__ edges,
                                                   const int* __restrict__ row_ptr,
                                                   const float* __restrict__ deg_inv,
                                                   float* __restrict__ out,
                                                   int widx) {
    int wid = threadIdx.x >> 6;
    int lane = threadIdx.x & 63;
    int n = blockIdx.x * 4 + wid;          // grid covers exactly N_NODES
    int beg = row_ptr[n], end = row_ptr[n + 1];
    float ax = 0.f, ay = 0.f;
    int i = beg;
    for (; i + 1 < end; i += 2) {
        const int4 e0 = edges[i];
        const int4 e1 = edges[i + 1];
        float w0 = __int_as_float(widx ? e0.z : e0.y);
        float w1 = __int_as_float(widx ? e1.z : e1.y);
        const ushort2 u0 = *reinterpret_cast<const ushort2*>(&xin[(long)e0.x * D + lane * 2]);
        const ushort2 u1 = *reinterpret_cast<const ushort2*>(&xin[(long)e1.x * D + lane * 2]);
        ax += w0 * bf2f(u0.x) + w1 * bf2f(u1.x);
        ay += w0 * bf2f(u0.y) + w1 * bf2f(u1.y);
    }
    if (i < end) {
        const int4 e0 = edges[i];
        float w0 = __int_as_float(widx ? e0.z : e0.y);
        const ushort2 u0 = *reinterpret_cast<const ushort2*>(&xin[(long)e0.x * D + lane * 2]);
        ax += w0 * bf2f(u0.x);
        ay += w0 * bf2f(u0.y);
    }
    float di = deg_inv[n];
    ax *= di; ay *= di;
    ax = ax > 0.f ? ax : 0.01f * ax;
    ay = ay > 0.f ? ay : 0.01f * ay;
    float2 r; r.x = ax; r.y = ay;
    *reinterpret_cast<float2*>(&out[(long)n * D + lane * 2]) = r;
}

// ---------------- Fused dual GEMM: out = relu([in1|in2] @ W + b) ----------------
// optionally also emits bf16 copy of out (for next layer's SpMM gathers)

__global__ __launch_bounds__(256) void gemm_dual_kernel(const float* __restrict__ in1,
                                                        const float* __restrict__ in2,
                                                        const float* __restrict__ W,
                                                        const float* __restrict__ bias,
                                                        float* __restrict__ out,
                                                        ushort* __restrict__ out_bf16) {
    __shared__ float As[KC][BM + APAD];
    __shared__ float Ws[KC][D];
    int tid = threadIdx.x;
    int tc = tid & 15;       // 16 col groups
    int tr = tid >> 4;       // 16 row groups
    int c0 = tc * 8;
    int r0g = blockIdx.x * BM;

    float acc[8][8];
#pragma unroll
    for (int j = 0; j < 8; ++j)
#pragma unroll
        for (int i = 0; i < 8; ++i) acc[j][i] = 0.f;

    for (int ch = 0; ch < 8; ++ch) {
        const float* src = (ch < 4) ? in1 : in2;
        int kb  = (ch & 3) * KC;   // col offset within source
        int wkb = ch * KC;         // row offset within W

        // stage A transposed: As[k][row]
        {
            int kk4  = (tid & 7) * 4;
            int rown = tid >> 3;    // 0..31
#pragma unroll
            for (int it = 0; it < 4; ++it) {
                int row = rown + it * 32;
                int gr = r0g + row;
                if (gr >= N_NODES) gr = N_NODES - 1;
                const float4 v = *reinterpret_cast<const float4*>(&src[(long)gr * D + kb + kk4]);
                As[kk4 + 0][row] = v.x;
                As[kk4 + 1][row] = v.y;
                As[kk4 + 2][row] = v.z;
                As[kk4 + 3][row] = v.w;
            }
        }
        // stage W
        {
            int c4  = (tid & 31) * 4;
            int kk0 = tid >> 5;     // 0..7
#pragma unroll
            for (int it = 0; it < 4; ++it) {
                int kk = kk0 + it * 8;
                *reinterpret_cast<float4*>(&Ws[kk][c4]) =
                    *reinterpret_cast<const float4*>(&W[(long)(wkb + kk) * D + c4]);
            }
        }
        __syncthreads();

#pragma unroll 8
        for (int kk = 0; kk < KC; ++kk) {
            float a[8], w[8];
#pragma unroll
            for (int j = 0; j < 8; ++j) a[j] = As[kk][tr * 8 + j];
#pragma unroll
            for (int i = 0; i < 8; ++i) w[i] = Ws[kk][c0 + i];
#pragma unroll
            for (int j = 0; j < 8; ++j)
#pragma unroll
                for (int i = 0; i < 8; ++i) acc[j][i] += a[j] * w[i];
        }
        __syncthreads();
    }

#pragma unroll
    for (int j = 0; j < 8; ++j) {
        int row = r0g + tr * 8 + j;
        if (row < N_NODES) {
            float v[8];
#pragma unroll
            for (int i = 0; i < 8; ++i) {
                float t = acc[j][i] + bias[c0 + i];
                v[i] = t > 0.f ? t : 0.f;
            }
            float4* po = reinterpret_cast<float4*>(&out[(long)row * D + c0]);
            po[0] = make_float4(v[0], v[1], v[2], v[3]);
            po[1] = make_float4(v[4], v[5], v[6], v[7]);
            if (out_bf16) {
                ushort4 u0, u1;
                u0.x = f2bf(v[0]); u0.y = f2bf(v[1]); u0.z = f2bf(v[2]); u0.w = f2bf(v[3]);
                u1.x = f2bf(v[4]); u1.y = f2bf(v[5]); u1.z = f2bf(v[6]); u1.w = f2bf(v[7]);
                ushort4* pb = reinterpret_cast<ushort4*>(&out_bf16[(long)row * D + c0]);
                pb[0] = u0;
                pb[1] = u1;
            }
        }
    }
}

// ---------------- Classifier: out = relu(H @ Wl1 + bl1) @ Wl2 + bl2 ----------------

__global__ __launch_bounds__(256) void cls_kernel(const float* __restrict__ H,
                                                  const float* __restrict__ Wl1,
                                                  const float* __restrict__ bl1,
                                                  const float* __restrict__ Wl2,
                                                  const float* __restrict__ bl2,
                                                  float* __restrict__ out) {
    __shared__ float As[KC][BM + APAD];
    __shared__ float Ws[KC][D];
    __shared__ float red[BM][2][16];
    int tid = threadIdx.x;
    int tc = tid & 15;
    int tr = tid >> 4;
    int c0 = tc * 8;
    int r0g = blockIdx.x * BM;

    float acc[8][8];
#pragma unroll
    for (int j = 0; j < 8; ++j)
#pragma unroll
        for (int i = 0; i < 8; ++i) acc[j][i] = 0.f;

    for (int ch = 0; ch < 4; ++ch) {
        int kb = ch * KC;
        {
            int kk4  = (tid & 7) * 4;
            int rown = tid >> 3;
#pragma unroll
            for (int it = 0; it < 4; ++it) {
                int row = rown + it * 32;
                int gr = r0g + row;
                if (gr >= N_NODES) gr = N_NODES - 1;
                const float4 v = *reinterpret_cast<const float4*>(&H[(long)gr * D + kb + kk4]);
                As[kk4 + 0][row] = v.x;
                As[kk4 + 1][row] = v.y;
                As[kk4 + 2][row] = v.z;
                As[kk4 + 3][row] = v.w;
            }
        }
        {
            int c4  = (tid & 31) * 4;
            int kk0 = tid >> 5;
#pragma unroll
            for (int it = 0; it < 4; ++it) {
                int kk = kk0 + it * 8;
                *reinterpret_cast<float4*>(&Ws[kk][c4]) =
                    *reinterpret_cast<const float4*>(&Wl1[(long)(kb + kk) * D + c4]);
            }
        }
        __syncthreads();

#pragma unroll 8
        for (int kk = 0; kk < KC; ++kk) {
            float a[8], w[8];
#pragma unroll
            for (int j = 0; j < 8; ++j) a[j] = As[kk][tr * 8 + j];
#pragma unroll
            for (int i = 0; i < 8; ++i) w[i] = Ws[kk][c0 + i];
#pragma unroll
            for (int j = 0; j < 8; ++j)
#pragma unroll
                for (int i = 0; i < 8; ++i) acc[j][i] += a[j] * w[i];
        }
        __syncthreads();
    }

    // epilogue: t = relu(acc + bl1), partial dot with Wl2 columns
    float w20[8], w21[8];
#pragma unroll
    for (int i = 0; i < 8; ++i) {
        w20[i] = Wl2[(c0 + i) * 2 + 0];
        w21[i] = Wl2[(c0 + i) * 2 + 1];
    }
#pragma unroll
    for (int j = 0; j < 8; ++j) {
        float p0 = 0.f, p1 = 0.f;
#pragma unroll
        for (int i = 0; i < 8; ++i) {
            float t = acc[j][i] + bl1[c0 + i];
            t = t > 0.f ? t : 0.f;
            p0 += t * w20[i];
            p1 += t * w21[i];
        }
        red[tr * 8 + j][0][tc] = p0;
        red[tr * 8 + j][1][tc] = p1;
    }
    __syncthreads();
    {
        int rl = tid >> 1, m = tid & 1;
        float s = bl2[m];
#pragma unroll
        for (int t = 0; t < 16; ++t) s += red[rl][m][t];
        int grow = r0g + rl;
        if (grow < N_NODES) out[(long)grow * 2 + m] = s;
    }
}

// ---------------- launch ----------------

extern "C" void kernel_launch(void* const* d_in, const int* in_sizes, int n_in,
                              void* d_out, int out_size, void* d_ws, size_t ws_size,
                              hipStream_t stream) {
    const float* x   = (const float*)d_in[0];
    const int* esrc  = (const int*)d_in[1];
    const int* edst  = (const int*)d_in[2];
    const float* ew1 = (const float*)d_in[3];
    const float* ew2 = (const float*)d_in[4];
    const float* W1  = (const float*)d_in[5];
    const float* b1  = (const float*)d_in[6];
    const float* W2  = (const float*)d_in[7];
    const float* b2  = (const float*)d_in[8];
    const float* Wl1 = (const float*)d_in[9];
    const float* bl1 = (const float*)d_in[10];
    const float* Wl2 = (const float*)d_in[11];
    const float* bl2 = (const float*)d_in[12];
    float* out = (float*)d_out;

    char* p = (char*)d_ws;
    float* A        = (float*)p;           p += (size_t)N_NODES * D * 4;   // agg / h2
    float* B        = (float*)p;           p += (size_t)N_NODES * D * 4;   // h1
    ushort* h1_bf16 = (ushort*)p;          p += (size_t)N_NODES * D * 2;
    float* deg_inv  = (float*)p;           p += (size_t)N_NODES * 4;
    int* deg        = (int*)p;             p += (size_t)N_NODES * 4;
    int* row_ptr    = (int*)p;             p += (size_t)(N_NODES + 1) * 4;
    int* blocksums  = (int*)p;             p += 128 * 4;
    int* blockoff   = (int*)p;             p += 128 * 4;
    int4* packed    = (int4*)p;            p += (size_t)N_EDGES * 16;
    // aliases inside B (dead before gemm1 writes B):
    int* rank       = (int*)B;                              // 6.4 MB
    ushort* x_bf16  = (ushort*)(B + (size_t)N_EDGES);       // 25.6 MB, after rank

    hipMemsetAsync(deg, 0, (size_t)N_NODES * 4, stream);

    int egrid = (N_EDGES + 255) / 256;
    hist_kernel<<<egrid, 256, 0, stream>>>(edst, deg, rank);
    scan1_kernel<<<SCAN_NBLK, SCAN_THR, 0, stream>>>(deg, blocksums);
    scan2_kernel<<<1, 128, 0, stream>>>(blocksums, blockoff, row_ptr);
    scan3_kernel<<<SCAN_NBLK, SCAN_THR, 0, stream>>>(deg, blockoff, row_ptr, deg_inv);
    scatter_kernel<<<egrid, 256, 0, stream>>>(esrc, edst, ew1, ew2, rank, row_ptr, packed);
    cvt_bf16_kernel<<<(N_NODES * D) / (256 * 8), 256, 0, stream>>>(x, x_bf16);

    int ggrid = (N_NODES + BM - 1) / BM;   // 782

    // layer 1
    spmm_kernel<<<N_NODES / 4, 256, 0, stream>>>(x_bf16, packed, row_ptr, deg_inv, A, 0);
    gemm_dual_kernel<<<ggrid, 256, 0, stream>>>(x, A, W1, b1, B, h1_bf16);
    // layer 2
    spmm_kernel<<<N_NODES / 4, 256, 0, stream>>>(h1_bf16, packed, row_ptr, deg_inv, A, 1);
    gemm_dual_kernel<<<ggrid, 256, 0, stream>>>(B, A, W2, b2, A, nullptr);  // h2 overwrites A
    // classifier
    cls_kernel<<<ggrid, 256, 0, stream>>>(A, Wl1, bl1, Wl2, bl2, out);
}

// Round 5
// 457.209 us; speedup vs baseline: 2.2860x; 1.2470x over previous
//
#include <hip/hip_runtime.h>

#define N_NODES 100000
#define N_EDGES 1600000
#define D 128

typedef __attribute__((ext_vector_type(8))) short bf16x8;
typedef __attribute__((ext_vector_type(4))) float f32x4;

__device__ __forceinline__ ushort f2bf(float f) {
    unsigned u = __float_as_uint(f);
    u += 0x7FFFu + ((u >> 16) & 1u);   // RNE
    return (ushort)(u >> 16);
}
__device__ __forceinline__ float bf2f(ushort u) {
    return __uint_as_float(((unsigned)u) << 16);
}

// ---------------- CSR build ----------------

__global__ __launch_bounds__(256) void hist_kernel(const int* __restrict__ dst,
                                                   int* __restrict__ deg,
                                                   int* __restrict__ rank) {
    int i = blockIdx.x * 256 + threadIdx.x;
    if (i < N_EDGES) rank[i] = atomicAdd(&deg[dst[i]], 1);
}

#define SCAN_BLK 1024
#define SCAN_THR 256
#define SCAN_NBLK ((N_NODES + SCAN_BLK - 1) / SCAN_BLK)   // 98

__global__ __launch_bounds__(SCAN_THR) void scan1_kernel(const int* __restrict__ deg,
                                                         int* __restrict__ blocksums) {
    __shared__ int sums[SCAN_THR];
    int tid = threadIdx.x;
    int base = blockIdx.x * SCAN_BLK + tid * 4;
    int s = 0;
    if (base + 3 < N_NODES) {
        const int4 v = *reinterpret_cast<const int4*>(&deg[base]);
        s = v.x + v.y + v.z + v.w;
    } else {
#pragma unroll
        for (int i = 0; i < 4; ++i)
            if (base + i < N_NODES) s += deg[base + i];
    }
    sums[tid] = s;
    __syncthreads();
#pragma unroll
    for (int off = SCAN_THR / 2; off > 0; off >>= 1) {
        if (tid < off) sums[tid] += sums[tid + off];
        __syncthreads();
    }
    if (tid == 0) blocksums[blockIdx.x] = sums[0];
}

__global__ __launch_bounds__(128) void scan2_kernel(const int* __restrict__ blocksums,
                                                    int* __restrict__ blockoff,
                                                    int* __restrict__ row_ptr) {
    __shared__ int s[128];
    int tid = threadIdx.x;
    int v = (tid < SCAN_NBLK) ? blocksums[tid] : 0;
    s[tid] = v;
    __syncthreads();
    for (int off = 1; off < 128; off <<= 1) {
        int t = (tid >= off) ? s[tid - off] : 0;
        __syncthreads();
        s[tid] += t;
        __syncthreads();
    }
    if (tid < SCAN_NBLK) blockoff[tid] = s[tid] - v;   // exclusive
    if (tid == 127) row_ptr[N_NODES] = s[127];         // grand total
}

__global__ __launch_bounds__(SCAN_THR) void scan3_kernel(const int* __restrict__ deg,
                                                         const int* __restrict__ blockoff,
                                                         int* __restrict__ row_ptr,
                                                         float* __restrict__ deg_inv) {
    __shared__ int tsum[SCAN_THR];
    int tid = threadIdx.x;
    int base = blockIdx.x * SCAN_BLK + tid * 4;
    int d[4];
#pragma unroll
    for (int i = 0; i < 4; ++i)
        d[i] = (base + i < N_NODES) ? deg[base + i] : 0;
    int s = d[0] + d[1] + d[2] + d[3];
    tsum[tid] = s;
    __syncthreads();
    for (int off = 1; off < SCAN_THR; off <<= 1) {
        int t = (tid >= off) ? tsum[tid - off] : 0;
        __syncthreads();
        tsum[tid] += t;
        __syncthreads();
    }
    int run = blockoff[blockIdx.x] + tsum[tid] - s;    // exclusive start
#pragma unroll
    for (int i = 0; i < 4; ++i) {
        int idx = base + i;
        if (idx < N_NODES) {
            row_ptr[idx] = run;
            deg_inv[idx] = d[i] > 0 ? 1.0f / (float)d[i] : 0.0f;
            run += d[i];
        }
    }
}

// atomic-free scatter: one 16B packed write per edge
__global__ __launch_bounds__(256) void scatter_kernel(const int* __restrict__ src,
                                                      const int* __restrict__ dst,
                                                      const float* __restrict__ w1,
                                                      const float* __restrict__ w2,
                                                      const int* __restrict__ rank,
                                                      const int* __restrict__ row_ptr,
                                                      int4* __restrict__ packed) {
    int i = blockIdx.x * 256 + threadIdx.x;
    if (i < N_EDGES) {
        int d = dst[i];
        int p = row_ptr[d] + rank[i];
        int4 e;
        e.x = src[i];
        e.y = __float_as_int(w1[i]);
        e.z = __float_as_int(w2[i]);
        e.w = 0;
        packed[p] = e;
    }
}

// ---------------- fp32 -> bf16 convert (8 elems/thread) ----------------

__global__ __launch_bounds__(256) void cvt_bf16_kernel(const float* __restrict__ in,
                                                       ushort* __restrict__ out) {
    long i = ((long)blockIdx.x * 256 + threadIdx.x) * 8;
    const float4 a = *reinterpret_cast<const float4*>(&in[i]);
    const float4 b = *reinterpret_cast<const float4*>(&in[i + 4]);
    ushort4 u0, u1;
    u0.x = f2bf(a.x); u0.y = f2bf(a.y); u0.z = f2bf(a.z); u0.w = f2bf(a.w);
    u1.x = f2bf(b.x); u1.y = f2bf(b.y); u1.z = f2bf(b.z); u1.w = f2bf(b.w);
    *reinterpret_cast<ushort4*>(&out[i]) = u0;
    *reinterpret_cast<ushort4*>(&out[i + 4]) = u1;
}

// ---------------- W tiling: fragment-ordered hi/lo split ----------------
// addr(k,n) = ((k>>3)*128 + n)*8 + (k&7)  -> b-frag for (kgroup, n) is 16B contiguous

__global__ __launch_bounds__(256) void wtile_kernel(const float* __restrict__ W,
                                                    ushort* __restrict__ th,
                                                    ushort* __restrict__ tl,
                                                    int total) {
    int i = blockIdx.x * 256 + threadIdx.x;
    if (i < total) {
        int k = i >> 7, n = i & 127;
        float v = W[i];
        ushort h = f2bf(v);
        ushort lo = f2bf(v - bf2f(h));
        int addr = (((k >> 3) << 7) + n) * 8 + (k & 7);
        th[addr] = h;
        tl[addr] = lo;
    }
}

// ---------------- SpMM (CSR gather of bf16 rows, fp32 accum, mean + leaky-relu) ----

__global__ __launch_bounds__(256) void spmm_kernel(const ushort* __restrict__ xin,
                                                   const int4* __restrict__ edges,
                                                   const int* __restrict__ row_ptr,
                                                   const float* __restrict__ deg_inv,
                                                   float* __restrict__ out,
                                                   int widx) {
    int wid = threadIdx.x >> 6;
    int lane = threadIdx.x & 63;
    int n = blockIdx.x * 4 + wid;
    int beg = row_ptr[n], end = row_ptr[n + 1];
    float ax = 0.f, ay = 0.f;
    int i = beg;
    for (; i + 1 < end; i += 2) {
        const int4 e0 = edges[i];
        const int4 e1 = edges[i + 1];
        float w0 = __int_as_float(widx ? e0.z : e0.y);
        float w1 = __int_as_float(widx ? e1.z : e1.y);
        const ushort2 u0 = *reinterpret_cast<const ushort2*>(&xin[(long)e0.x * D + lane * 2]);
        const ushort2 u1 = *reinterpret_cast<const ushort2*>(&xin[(long)e1.x * D + lane * 2]);
        ax += w0 * bf2f(u0.x) + w1 * bf2f(u1.x);
        ay += w0 * bf2f(u0.y) + w1 * bf2f(u1.y);
    }
    if (i < end) {
        const int4 e0 = edges[i];
        float w0 = __int_as_float(widx ? e0.z : e0.y);
        const ushort2 u0 = *reinterpret_cast<const ushort2*>(&xin[(long)e0.x * D + lane * 2]);
        ax += w0 * bf2f(u0.x);
        ay += w0 * bf2f(u0.y);
    }
    float di = deg_inv[n];
    ax *= di; ay *= di;
    ax = ax > 0.f ? ax : 0.01f * ax;
    ay = ay > 0.f ? ay : 0.01f * ay;
    float2 r; r.x = ax; r.y = ay;
    *reinterpret_cast<float2*>(&out[(long)n * D + lane * 2]) = r;
}

// ---------------- MFMA split-precision GEMM ----------------
// out = relu([in1|in2] @ W + b), emitted as bf16 hi/lo pair.
// LDS-free: per-wave 32 rows; A-frags from global (converted in-reg),
// B-frags from pre-tiled W (L2-resident). 3 MFMA per tile: ah*bh + al*bh + ah*bl.

__device__ __forceinline__ void load_split8(const float* __restrict__ p,
                                            bf16x8& h, bf16x8& l) {
    const float4 f0 = *reinterpret_cast<const float4*>(p);
    const float4 f1 = *reinterpret_cast<const float4*>(p + 4);
    float f[8] = {f0.x, f0.y, f0.z, f0.w, f1.x, f1.y, f1.z, f1.w};
#pragma unroll
    for (int j = 0; j < 8; ++j) {
        ushort hh = f2bf(f[j]);
        h[j] = (short)hh;
        l[j] = (short)f2bf(f[j] - bf2f(hh));
    }
}

template<bool IN1_BF16>
__global__ __launch_bounds__(256) void gemm_mfma_kernel(
        const float* __restrict__ in1f,
        const ushort* __restrict__ in1h, const ushort* __restrict__ in1l,
        const float* __restrict__ in2f,
        const ushort* __restrict__ Wth, const ushort* __restrict__ Wtl,
        const float* __restrict__ bias,
        ushort* __restrict__ outh, ushort* __restrict__ outl) {
    int tid = threadIdx.x;
    int w = tid >> 6, l = tid & 63;
    int c = l & 15, kg = l >> 4;
    int base_m = blockIdx.x * 128 + w * 32;
    int r0 = base_m + c;       if (r0 >= N_NODES) r0 = N_NODES - 1;
    int r1 = base_m + 16 + c;  if (r1 >= N_NODES) r1 = N_NODES - 1;

    f32x4 acc0[8], acc1[8];
#pragma unroll
    for (int ni = 0; ni < 8; ++ni) { acc0[ni] = (f32x4)0.f; acc1[ni] = (f32x4)0.f; }

    for (int ks = 0; ks < 8; ++ks) {
        int kb = (ks & 3) * 32 + kg * 8;
        bf16x8 ah0, al0, ah1, al1;
        if (ks < 4) {
            if constexpr (IN1_BF16) {
                ah0 = *reinterpret_cast<const bf16x8*>(&in1h[(long)r0 * D + kb]);
                al0 = *reinterpret_cast<const bf16x8*>(&in1l[(long)r0 * D + kb]);
                ah1 = *reinterpret_cast<const bf16x8*>(&in1h[(long)r1 * D + kb]);
                al1 = *reinterpret_cast<const bf16x8*>(&in1l[(long)r1 * D + kb]);
            } else {
                load_split8(&in1f[(long)r0 * D + kb], ah0, al0);
                load_split8(&in1f[(long)r1 * D + kb], ah1, al1);
            }
        } else {
            load_split8(&in2f[(long)r0 * D + kb], ah0, al0);
            load_split8(&in2f[(long)r1 * D + kb], ah1, al1);
        }
        const ushort* wb  = &Wth[(size_t)((ks * 4 + kg) * 128) * 8];
        const ushort* wbl = &Wtl[(size_t)((ks * 4 + kg) * 128) * 8];
#pragma unroll
        for (int ni = 0; ni < 8; ++ni) {
            const bf16x8 bh = *reinterpret_cast<const bf16x8*>(&wb[(ni * 16 + c) * 8]);
            const bf16x8 bl = *reinterpret_cast<const bf16x8*>(&wbl[(ni * 16 + c) * 8]);
            acc0[ni] = __builtin_amdgcn_mfma_f32_16x16x32_bf16(ah0, bh, acc0[ni], 0, 0, 0);
            acc0[ni] = __builtin_amdgcn_mfma_f32_16x16x32_bf16(al0, bh, acc0[ni], 0, 0, 0);
            acc0[ni] = __builtin_amdgcn_mfma_f32_16x16x32_bf16(ah0, bl, acc0[ni], 0, 0, 0);
            acc1[ni] = __builtin_amdgcn_mfma_f32_16x16x32_bf16(ah1, bh, acc1[ni], 0, 0, 0);
            acc1[ni] = __builtin_amdgcn_mfma_f32_16x16x32_bf16(al1, bh, acc1[ni], 0, 0, 0);
            acc1[ni] = __builtin_amdgcn_mfma_f32_16x16x32_bf16(ah1, bl, acc1[ni], 0, 0, 0);
        }
    }

    float bv[8];
#pragma unroll
    for (int ni = 0; ni < 8; ++ni) bv[ni] = bias[ni * 16 + c];
#pragma unroll
    for (int mi = 0; mi < 2; ++mi) {
        int rowb = base_m + mi * 16 + kg * 4;
#pragma unroll
        for (int r = 0; r < 4; ++r) {
            int row = rowb + r;
            if (row < N_NODES) {
#pragma unroll
                for (int ni = 0; ni < 8; ++ni) {
                    float v = (mi ? acc1[ni][r] : acc0[ni][r]) + bv[ni];
                    v = v > 0.f ? v : 0.f;
                    ushort hh = f2bf(v);
                    outh[(long)row * D + ni * 16 + c] = hh;
                    outl[(long)row * D + ni * 16 + c] = f2bf(v - bf2f(hh));
                }
            }
        }
    }
}

// ---------------- Classifier: out = relu(H @ Wl1 + bl1) @ Wl2 + bl2 ----------------

__global__ __launch_bounds__(256) void cls_mfma_kernel(
        const ushort* __restrict__ Hh, const ushort* __restrict__ Hl,
        const ushort* __restrict__ Wth, const ushort* __restrict__ Wtl,
        const float* __restrict__ bl1, const float* __restrict__ Wl2,
        const float* __restrict__ bl2, float* __restrict__ out) {
    int tid = threadIdx.x;
    int w = tid >> 6, l = tid & 63;
    int c = l & 15, kg = l >> 4;
    int base_m = blockIdx.x * 128 + w * 32;
    int r0 = base_m + c;       if (r0 >= N_NODES) r0 = N_NODES - 1;
    int r1 = base_m + 16 + c;  if (r1 >= N_NODES) r1 = N_NODES - 1;

    f32x4 acc0[8], acc1[8];
#pragma unroll
    for (int ni = 0; ni < 8; ++ni) { acc0[ni] = (f32x4)0.f; acc1[ni] = (f32x4)0.f; }

    for (int ks = 0; ks < 4; ++ks) {
        int kb = ks * 32 + kg * 8;
        bf16x8 ah0 = *reinterpret_cast<const bf16x8*>(&Hh[(long)r0 * D + kb]);
        bf16x8 al0 = *reinterpret_cast<const bf16x8*>(&Hl[(long)r0 * D + kb]);
        bf16x8 ah1 = *reinterpret_cast<const bf16x8*>(&Hh[(long)r1 * D + kb]);
        bf16x8 al1 = *reinterpret_cast<const bf16x8*>(&Hl[(long)r1 * D + kb]);
        const ushort* wb  = &Wth[(size_t)((ks * 4 + kg) * 128) * 8];
        const ushort* wbl = &Wtl[(size_t)((ks * 4 + kg) * 128) * 8];
#pragma unroll
        for (int ni = 0; ni < 8; ++ni) {
            const bf16x8 bh = *reinterpret_cast<const bf16x8*>(&wb[(ni * 16 + c) * 8]);
            const bf16x8 bl = *reinterpret_cast<const bf16x8*>(&wbl[(ni * 16 + c) * 8]);
            acc0[ni] = __builtin_amdgcn_mfma_f32_16x16x32_bf16(ah0, bh, acc0[ni], 0, 0, 0);
            acc0[ni] = __builtin_amdgcn_mfma_f32_16x16x32_bf16(al0, bh, acc0[ni], 0, 0, 0);
            acc0[ni] = __builtin_amdgcn_mfma_f32_16x16x32_bf16(ah0, bl, acc0[ni], 0, 0, 0);
            acc1[ni] = __builtin_amdgcn_mfma_f32_16x16x32_bf16(ah1, bh, acc1[ni], 0, 0, 0);
            acc1[ni] = __builtin_amdgcn_mfma_f32_16x16x32_bf16(al1, bh, acc1[ni], 0, 0, 0);
            acc1[ni] = __builtin_amdgcn_mfma_f32_16x16x32_bf16(ah1, bl, acc1[ni], 0, 0, 0);
        }
    }

    float b1v[8]; float2 w2v[8];
#pragma unroll
    for (int ni = 0; ni < 8; ++ni) {
        b1v[ni] = bl1[ni * 16 + c];
        w2v[ni] = *reinterpret_cast<const float2*>(&Wl2[(ni * 16 + c) * 2]);
    }
#pragma unroll
    for (int mi = 0; mi < 2; ++mi) {
        float p0[4] = {0.f, 0.f, 0.f, 0.f};
        float p1[4] = {0.f, 0.f, 0.f, 0.f};
#pragma unroll
        for (int ni = 0; ni < 8; ++ni) {
#pragma unroll
            for (int r = 0; r < 4; ++r) {
                float t = (mi ? acc1[ni][r] : acc0[ni][r]) + b1v[ni];
                t = t > 0.f ? t : 0.f;
                p0[r] += t * w2v[ni].x;
                p1[r] += t * w2v[ni].y;
            }
        }
#pragma unroll
        for (int r = 0; r < 4; ++r) {
#pragma unroll
            for (int m = 1; m < 16; m <<= 1) {
                p0[r] += __shfl_xor(p0[r], m, 64);
                p1[r] += __shfl_xor(p1[r], m, 64);
            }
        }
        if (c < 2) {
            int rowb = base_m + mi * 16 + kg * 4;
#pragma unroll
            for (int r = 0; r < 4; ++r) {
                int row = rowb + r;
                if (row < N_NODES)
                    out[(long)row * 2 + c] = (c == 0 ? p0[r] : p1[r]) + bl2[c];
            }
        }
    }
}

// ---------------- launch ----------------

extern "C" void kernel_launch(void* const* d_in, const int* in_sizes, int n_in,
                              void* d_out, int out_size, void* d_ws, size_t ws_size,
                              hipStream_t stream) {
    const float* x   = (const float*)d_in[0];
    const int* esrc  = (const int*)d_in[1];
    const int* edst  = (const int*)d_in[2];
    const float* ew1 = (const float*)d_in[3];
    const float* ew2 = (const float*)d_in[4];
    const float* W1  = (const float*)d_in[5];
    const float* b1  = (const float*)d_in[6];
    const float* W2  = (const float*)d_in[7];
    const float* b2  = (const float*)d_in[8];
    const float* Wl1 = (const float*)d_in[9];
    const float* bl1 = (const float*)d_in[10];
    const float* Wl2 = (const float*)d_in[11];
    const float* bl2 = (const float*)d_in[12];
    float* out = (float*)d_out;

    char* p = (char*)d_ws;
    float* A        = (float*)p;           p += (size_t)N_NODES * D * 4;   // agg (fp32)
    ushort* h1h     = (ushort*)p;          p += (size_t)N_NODES * D * 2;   // h1/h2 hi (aliased)
    ushort* h1l     = (ushort*)p;          p += (size_t)N_NODES * D * 2;   // h1/h2 lo
    float* deg_inv  = (float*)p;           p += (size_t)N_NODES * 4;
    int* deg        = (int*)p;             p += (size_t)N_NODES * 4;
    int* row_ptr    = (int*)p;             p += (size_t)(N_NODES + 16) * 4;
    int* blocksums  = (int*)p;             p += 128 * 4;
    int* blockoff   = (int*)p;             p += 128 * 4;
    int4* packed    = (int4*)p;            p += (size_t)N_EDGES * 16;
    ushort* xbf     = (ushort*)p;          p += (size_t)N_NODES * D * 2;
    ushort* W1th    = (ushort*)p;          p += 2 * D * D * 2;
    ushort* W1tl    = (ushort*)p;          p += 2 * D * D * 2;
    ushort* W2th    = (ushort*)p;          p += 2 * D * D * 2;
    ushort* W2tl    = (ushort*)p;          p += 2 * D * D * 2;
    ushort* Wl1th   = (ushort*)p;          p += D * D * 2;
    ushort* Wl1tl   = (ushort*)p;          p += D * D * 2;
    int* rank       = (int*)xbf;           // rank dead before cvt writes xbf

    hipMemsetAsync(deg, 0, (size_t)N_NODES * 4, stream);

    int egrid = (N_EDGES + 255) / 256;
    hist_kernel<<<egrid, 256, 0, stream>>>(edst, deg, rank);
    scan1_kernel<<<SCAN_NBLK, SCAN_THR, 0, stream>>>(deg, blocksums);
    scan2_kernel<<<1, 128, 0, stream>>>(blocksums, blockoff, row_ptr);
    scan3_kernel<<<SCAN_NBLK, SCAN_THR, 0, stream>>>(deg, blockoff, row_ptr, deg_inv);
    scatter_kernel<<<egrid, 256, 0, stream>>>(esrc, edst, ew1, ew2, rank, row_ptr, packed);
    cvt_bf16_kernel<<<(N_NODES * D) / (256 * 8), 256, 0, stream>>>(x, xbf);
    wtile_kernel<<<(2 * D * D + 255) / 256, 256, 0, stream>>>(W1, W1th, W1tl, 2 * D * D);
    wtile_kernel<<<(2 * D * D + 255) / 256, 256, 0, stream>>>(W2, W2th, W2tl, 2 * D * D);
    wtile_kernel<<<(D * D + 255) / 256, 256, 0, stream>>>(Wl1, Wl1th, Wl1tl, D * D);

    int ggrid = (N_NODES + 127) / 128;   // 782

    // layer 1
    spmm_kernel<<<N_NODES / 4, 256, 0, stream>>>(xbf, packed, row_ptr, deg_inv, A, 0);
    gemm_mfma_kernel<false><<<ggrid, 256, 0, stream>>>(x, nullptr, nullptr, A,
                                                       W1th, W1tl, b1, h1h, h1l);
    // layer 2 (h2 overwrites h1 in place: each wave reads only its own 32 rows first)
    spmm_kernel<<<N_NODES / 4, 256, 0, stream>>>(h1h, packed, row_ptr, deg_inv, A, 1);
    gemm_mfma_kernel<true><<<ggrid, 256, 0, stream>>>(nullptr, h1h, h1l, A,
                                                      W2th, W2tl, b2, h1h, h1l);
    // classifier
    cls_mfma_kernel<<<ggrid, 256, 0, stream>>>(h1h, h1l, Wl1th, Wl1tl, bl1, Wl2, bl2, out);
}

// Round 6
// 404.998 us; speedup vs baseline: 2.5807x; 1.1289x over previous
//
#include <hip/hip_runtime.h>
#include <hip/hip_fp16.h>

#define N_NODES 100000
#define N_EDGES 1600000
#define D 128

typedef __attribute__((ext_vector_type(8))) short bf16x8;
typedef __attribute__((ext_vector_type(4))) float f32x4;

__device__ __forceinline__ ushort f2bf(float f) {
    unsigned u = __float_as_uint(f);
    u += 0x7FFFu + ((u >> 16) & 1u);   // RNE
    return (ushort)(u >> 16);
}
__device__ __forceinline__ float bf2f(ushort u) {
    return __uint_as_float(((unsigned)u) << 16);
}
__device__ __forceinline__ float h2f(ushort u) {
    __half_raw r; r.x = u;
    return __half2float(__half(r));
}
__device__ __forceinline__ ushort f2h(float f) {
    __half_raw r = __half_raw(__float2half(f));
    return r.x;
}

// ---------------- CSR build ----------------

__global__ __launch_bounds__(256) void hist_kernel(const int* __restrict__ dst,
                                                   int* __restrict__ deg,
                                                   int* __restrict__ rank) {
    int i = blockIdx.x * 256 + threadIdx.x;
    if (i < N_EDGES) rank[i] = atomicAdd(&deg[dst[i]], 1);
}

#define SCAN_BLK 1024
#define SCAN_THR 256
#define SCAN_NBLK ((N_NODES + SCAN_BLK - 1) / SCAN_BLK)   // 98

__global__ __launch_bounds__(SCAN_THR) void scan1_kernel(const int* __restrict__ deg,
                                                         int* __restrict__ blocksums) {
    __shared__ int sums[SCAN_THR];
    int tid = threadIdx.x;
    int base = blockIdx.x * SCAN_BLK + tid * 4;
    int s = 0;
    if (base + 3 < N_NODES) {
        const int4 v = *reinterpret_cast<const int4*>(&deg[base]);
        s = v.x + v.y + v.z + v.w;
    } else {
#pragma unroll
        for (int i = 0; i < 4; ++i)
            if (base + i < N_NODES) s += deg[base + i];
    }
    sums[tid] = s;
    __syncthreads();
#pragma unroll
    for (int off = SCAN_THR / 2; off > 0; off >>= 1) {
        if (tid < off) sums[tid] += sums[tid + off];
        __syncthreads();
    }
    if (tid == 0) blocksums[blockIdx.x] = sums[0];
}

__global__ __launch_bounds__(128) void scan2_kernel(const int* __restrict__ blocksums,
                                                    int* __restrict__ blockoff,
                                                    int* __restrict__ row_ptr) {
    __shared__ int s[128];
    int tid = threadIdx.x;
    int v = (tid < SCAN_NBLK) ? blocksums[tid] : 0;
    s[tid] = v;
    __syncthreads();
    for (int off = 1; off < 128; off <<= 1) {
        int t = (tid >= off) ? s[tid - off] : 0;
        __syncthreads();
        s[tid] += t;
        __syncthreads();
    }
    if (tid < SCAN_NBLK) blockoff[tid] = s[tid] - v;   // exclusive
    if (tid == 127) row_ptr[N_NODES] = s[127];         // grand total
}

__global__ __launch_bounds__(SCAN_THR) void scan3_kernel(const int* __restrict__ deg,
                                                         const int* __restrict__ blockoff,
                                                         int* __restrict__ row_ptr,
                                                         float* __restrict__ deg_inv) {
    __shared__ int tsum[SCAN_THR];
    int tid = threadIdx.x;
    int base = blockIdx.x * SCAN_BLK + tid * 4;
    int d[4];
#pragma unroll
    for (int i = 0; i < 4; ++i)
        d[i] = (base + i < N_NODES) ? deg[base + i] : 0;
    int s = d[0] + d[1] + d[2] + d[3];
    tsum[tid] = s;
    __syncthreads();
    for (int off = 1; off < SCAN_THR; off <<= 1) {
        int t = (tid >= off) ? tsum[tid - off] : 0;
        __syncthreads();
        tsum[tid] += t;
        __syncthreads();
    }
    int run = blockoff[blockIdx.x] + tsum[tid] - s;    // exclusive start
#pragma unroll
    for (int i = 0; i < 4; ++i) {
        int idx = base + i;
        if (idx < N_NODES) {
            row_ptr[idx] = run;
            deg_inv[idx] = d[i] > 0 ? 1.0f / (float)d[i] : 0.0f;
            run += d[i];
        }
    }
}

// atomic-free scatter: one random 8B write per edge.
// Weights pre-scaled by deg_inv[dst] (mean folded in), stored as fp16 pair.
__global__ __launch_bounds__(256) void scatter_kernel(const int* __restrict__ src,
                                                      const int* __restrict__ dst,
                                                      const float* __restrict__ w1,
                                                      const float* __restrict__ w2,
                                                      const int* __restrict__ rank,
                                                      const int* __restrict__ row_ptr,
                                                      const float* __restrict__ deg_inv,
                                                      uint2* __restrict__ packed) {
    int i = blockIdx.x * 256 + threadIdx.x;
    if (i < N_EDGES) {
        int d = dst[i];
        int p = row_ptr[d] + rank[i];
        float di = deg_inv[d];
        uint2 e;
        e.x = (unsigned)src[i];
        e.y = (unsigned)f2h(w1[i] * di) | ((unsigned)f2h(w2[i] * di) << 16);
        packed[p] = e;
    }
}

// ---------------- fp32 -> bf16 convert (8 elems/thread) ----------------

__global__ __launch_bounds__(256) void cvt_bf16_kernel(const float* __restrict__ in,
                                                       ushort* __restrict__ out) {
    long i = ((long)blockIdx.x * 256 + threadIdx.x) * 8;
    const float4 a = *reinterpret_cast<const float4*>(&in[i]);
    const float4 b = *reinterpret_cast<const float4*>(&in[i + 4]);
    ushort4 u0, u1;
    u0.x = f2bf(a.x); u0.y = f2bf(a.y); u0.z = f2bf(a.z); u0.w = f2bf(a.w);
    u1.x = f2bf(b.x); u1.y = f2bf(b.y); u1.z = f2bf(b.z); u1.w = f2bf(b.w);
    *reinterpret_cast<ushort4*>(&out[i]) = u0;
    *reinterpret_cast<ushort4*>(&out[i + 4]) = u1;
}

// ---------------- W tiling: fragment-ordered hi/lo split ----------------

__global__ __launch_bounds__(256) void wtile_kernel(const float* __restrict__ W,
                                                    ushort* __restrict__ th,
                                                    ushort* __restrict__ tl,
                                                    int total) {
    int i = blockIdx.x * 256 + threadIdx.x;
    if (i < total) {
        int k = i >> 7, n = i & 127;
        float v = W[i];
        ushort h = f2bf(v);
        ushort lo = f2bf(v - bf2f(h));
        int addr = (((k >> 3) << 7) + n) * 8 + (k & 7);
        th[addr] = h;
        tl[addr] = lo;
    }
}

// ---------------- SpMM: sum of pre-scaled gathers + leaky-relu ----------------
// wave-per-node; 32 lanes cover a row (ushort4/lane); lane-half = edge parity.
// One gather instruction fetches TWO edges' rows; 4 edges per iteration in flight.

__global__ __launch_bounds__(256) void spmm_kernel(const ushort* __restrict__ xin,
                                                   const uint2* __restrict__ edges,
                                                   const int* __restrict__ row_ptr,
                                                   float* __restrict__ out,
                                                   int widx) {
    int wid = threadIdx.x >> 6;
    int half = (threadIdx.x >> 5) & 1;     // edge parity handled by this lane-half
    int l = threadIdx.x & 31;              // dim group: dims 4l..4l+3
    int n = blockIdx.x * 4 + wid;
    int beg = row_ptr[n], end = row_ptr[n + 1];
    float a0 = 0.f, a1 = 0.f, a2 = 0.f, a3 = 0.f;

    int i = beg;
    for (; i + 3 < end; i += 4) {
        const uint2 e0 = edges[i + half];
        const uint2 e1 = edges[i + 2 + half];
        float w0 = h2f((ushort)(widx ? (e0.y >> 16) : (e0.y & 0xFFFFu)));
        float w1 = h2f((ushort)(widx ? (e1.y >> 16) : (e1.y & 0xFFFFu)));
        const ushort4 u0 = *reinterpret_cast<const ushort4*>(&xin[(long)e0.x * D + l * 4]);
        const ushort4 u1 = *reinterpret_cast<const ushort4*>(&xin[(long)e1.x * D + l * 4]);
        a0 += w0 * bf2f(u0.x) + w1 * bf2f(u1.x);
        a1 += w0 * bf2f(u0.y) + w1 * bf2f(u1.y);
        a2 += w0 * bf2f(u0.z) + w1 * bf2f(u1.z);
        a3 += w0 * bf2f(u0.w) + w1 * bf2f(u1.w);
    }
    if (i + 1 < end) {
        const uint2 e0 = edges[i + half];
        float w0 = h2f((ushort)(widx ? (e0.y >> 16) : (e0.y & 0xFFFFu)));
        const ushort4 u0 = *reinterpret_cast<const ushort4*>(&xin[(long)e0.x * D + l * 4]);
        a0 += w0 * bf2f(u0.x);
        a1 += w0 * bf2f(u0.y);
        a2 += w0 * bf2f(u0.z);
        a3 += w0 * bf2f(u0.w);
        i += 2;
    }
    if (i < end) {
        // odd tail: both halves load the last edge; half 1 contributes 0
        const uint2 e0 = edges[i];
        float w0 = half ? 0.f : h2f((ushort)(widx ? (e0.y >> 16) : (e0.y & 0xFFFFu)));
        const ushort4 u0 = *reinterpret_cast<const ushort4*>(&xin[(long)e0.x * D + l * 4]);
        a0 += w0 * bf2f(u0.x);
        a1 += w0 * bf2f(u0.y);
        a2 += w0 * bf2f(u0.z);
        a3 += w0 * bf2f(u0.w);
    }

    // combine the two edge-parity halves (lane ^ 32)
    a0 += __shfl_xor(a0, 32, 64);
    a1 += __shfl_xor(a1, 32, 64);
    a2 += __shfl_xor(a2, 32, 64);
    a3 += __shfl_xor(a3, 32, 64);

    if (half == 0) {
        a0 = a0 > 0.f ? a0 : 0.01f * a0;
        a1 = a1 > 0.f ? a1 : 0.01f * a1;
        a2 = a2 > 0.f ? a2 : 0.01f * a2;
        a3 = a3 > 0.f ? a3 : 0.01f * a3;
        *reinterpret_cast<float4*>(&out[(long)n * D + l * 4]) = make_float4(a0, a1, a2, a3);
    }
}

// ---------------- MFMA split-precision GEMM ----------------

__device__ __forceinline__ void load_split8(const float* __restrict__ p,
                                            bf16x8& h, bf16x8& l) {
    const float4 f0 = *reinterpret_cast<const float4*>(p);
    const float4 f1 = *reinterpret_cast<const float4*>(p + 4);
    float f[8] = {f0.x, f0.y, f0.z, f0.w, f1.x, f1.y, f1.z, f1.w};
#pragma unroll
    for (int j = 0; j < 8; ++j) {
        ushort hh = f2bf(f[j]);
        h[j] = (short)hh;
        l[j] = (short)f2bf(f[j] - bf2f(hh));
    }
}

template<bool IN1_BF16>
__global__ __launch_bounds__(256) void gemm_mfma_kernel(
        const float* __restrict__ in1f,
        const ushort* __restrict__ in1h, const ushort* __restrict__ in1l,
        const float* __restrict__ in2f,
        const ushort* __restrict__ Wth, const ushort* __restrict__ Wtl,
        const float* __restrict__ bias,
        ushort* __restrict__ outh, ushort* __restrict__ outl) {
    int tid = threadIdx.x;
    int w = tid >> 6, l = tid & 63;
    int c = l & 15, kg = l >> 4;
    int base_m = blockIdx.x * 128 + w * 32;
    int r0 = base_m + c;       if (r0 >= N_NODES) r0 = N_NODES - 1;
    int r1 = base_m + 16 + c;  if (r1 >= N_NODES) r1 = N_NODES - 1;

    f32x4 acc0[8], acc1[8];
#pragma unroll
    for (int ni = 0; ni < 8; ++ni) { acc0[ni] = (f32x4)0.f; acc1[ni] = (f32x4)0.f; }

    for (int ks = 0; ks < 8; ++ks) {
        int kb = (ks & 3) * 32 + kg * 8;
        bf16x8 ah0, al0, ah1, al1;
        if (ks < 4) {
            if constexpr (IN1_BF16) {
                ah0 = *reinterpret_cast<const bf16x8*>(&in1h[(long)r0 * D + kb]);
                al0 = *reinterpret_cast<const bf16x8*>(&in1l[(long)r0 * D + kb]);
                ah1 = *reinterpret_cast<const bf16x8*>(&in1h[(long)r1 * D + kb]);
                al1 = *reinterpret_cast<const bf16x8*>(&in1l[(long)r1 * D + kb]);
            } else {
                load_split8(&in1f[(long)r0 * D + kb], ah0, al0);
                load_split8(&in1f[(long)r1 * D + kb], ah1, al1);
            }
        } else {
            load_split8(&in2f[(long)r0 * D + kb], ah0, al0);
            load_split8(&in2f[(long)r1 * D + kb], ah1, al1);
        }
        const ushort* wb  = &Wth[(size_t)((ks * 4 + kg) * 128) * 8];
        const ushort* wbl = &Wtl[(size_t)((ks * 4 + kg) * 128) * 8];
#pragma unroll
        for (int ni = 0; ni < 8; ++ni) {
            const bf16x8 bh = *reinterpret_cast<const bf16x8*>(&wb[(ni * 16 + c) * 8]);
            const bf16x8 bl = *reinterpret_cast<const bf16x8*>(&wbl[(ni * 16 + c) * 8]);
            acc0[ni] = __builtin_amdgcn_mfma_f32_16x16x32_bf16(ah0, bh, acc0[ni], 0, 0, 0);
            acc0[ni] = __builtin_amdgcn_mfma_f32_16x16x32_bf16(al0, bh, acc0[ni], 0, 0, 0);
            acc0[ni] = __builtin_amdgcn_mfma_f32_16x16x32_bf16(ah0, bl, acc0[ni], 0, 0, 0);
            acc1[ni] = __builtin_amdgcn_mfma_f32_16x16x32_bf16(ah1, bh, acc1[ni], 0, 0, 0);
            acc1[ni] = __builtin_amdgcn_mfma_f32_16x16x32_bf16(al1, bh, acc1[ni], 0, 0, 0);
            acc1[ni] = __builtin_amdgcn_mfma_f32_16x16x32_bf16(ah1, bl, acc1[ni], 0, 0, 0);
        }
    }

    float bv[8];
#pragma unroll
    for (int ni = 0; ni < 8; ++ni) bv[ni] = bias[ni * 16 + c];
#pragma unroll
    for (int mi = 0; mi < 2; ++mi) {
        int rowb = base_m + mi * 16 + kg * 4;
#pragma unroll
        for (int r = 0; r < 4; ++r) {
            int row = rowb + r;
            if (row < N_NODES) {
#pragma unroll
                for (int ni = 0; ni < 8; ++ni) {
                    float v = (mi ? acc1[ni][r] : acc0[ni][r]) + bv[ni];
                    v = v > 0.f ? v : 0.f;
                    ushort hh = f2bf(v);
                    outh[(long)row * D + ni * 16 + c] = hh;
                    outl[(long)row * D + ni * 16 + c] = f2bf(v - bf2f(hh));
                }
            }
        }
    }
}

// ---------------- Classifier ----------------

__global__ __launch_bounds__(256) void cls_mfma_kernel(
        const ushort* __restrict__ Hh, const ushort* __restrict__ Hl,
        const ushort* __restrict__ Wth, const ushort* __restrict__ Wtl,
        const float* __restrict__ bl1, const float* __restrict__ Wl2,
        const float* __restrict__ bl2, float* __restrict__ out) {
    int tid = threadIdx.x;
    int w = tid >> 6, l = tid & 63;
    int c = l & 15, kg = l >> 4;
    int base_m = blockIdx.x * 128 + w * 32;
    int r0 = base_m + c;       if (r0 >= N_NODES) r0 = N_NODES - 1;
    int r1 = base_m + 16 + c;  if (r1 >= N_NODES) r1 = N_NODES - 1;

    f32x4 acc0[8], acc1[8];
#pragma unroll
    for (int ni = 0; ni < 8; ++ni) { acc0[ni] = (f32x4)0.f; acc1[ni] = (f32x4)0.f; }

    for (int ks = 0; ks < 4; ++ks) {
        int kb = ks * 32 + kg * 8;
        bf16x8 ah0 = *reinterpret_cast<const bf16x8*>(&Hh[(long)r0 * D + kb]);
        bf16x8 al0 = *reinterpret_cast<const bf16x8*>(&Hl[(long)r0 * D + kb]);
        bf16x8 ah1 = *reinterpret_cast<const bf16x8*>(&Hh[(long)r1 * D + kb]);
        bf16x8 al1 = *reinterpret_cast<const bf16x8*>(&Hl[(long)r1 * D + kb]);
        const ushort* wb  = &Wth[(size_t)((ks * 4 + kg) * 128) * 8];
        const ushort* wbl = &Wtl[(size_t)((ks * 4 + kg) * 128) * 8];
#pragma unroll
        for (int ni = 0; ni < 8; ++ni) {
            const bf16x8 bh = *reinterpret_cast<const bf16x8*>(&wb[(ni * 16 + c) * 8]);
            const bf16x8 bl = *reinterpret_cast<const bf16x8*>(&wbl[(ni * 16 + c) * 8]);
            acc0[ni] = __builtin_amdgcn_mfma_f32_16x16x32_bf16(ah0, bh, acc0[ni], 0, 0, 0);
            acc0[ni] = __builtin_amdgcn_mfma_f32_16x16x32_bf16(al0, bh, acc0[ni], 0, 0, 0);
            acc0[ni] = __builtin_amdgcn_mfma_f32_16x16x32_bf16(ah0, bl, acc0[ni], 0, 0, 0);
            acc1[ni] = __builtin_amdgcn_mfma_f32_16x16x32_bf16(ah1, bh, acc1[ni], 0, 0, 0);
            acc1[ni] = __builtin_amdgcn_mfma_f32_16x16x32_bf16(al1, bh, acc1[ni], 0, 0, 0);
            acc1[ni] = __builtin_amdgcn_mfma_f32_16x16x32_bf16(ah1, bl, acc1[ni], 0, 0, 0);
        }
    }

    float b1v[8]; float2 w2v[8];
#pragma unroll
    for (int ni = 0; ni < 8; ++ni) {
        b1v[ni] = bl1[ni * 16 + c];
        w2v[ni] = *reinterpret_cast<const float2*>(&Wl2[(ni * 16 + c) * 2]);
    }
#pragma unroll
    for (int mi = 0; mi < 2; ++mi) {
        float p0[4] = {0.f, 0.f, 0.f, 0.f};
        float p1[4] = {0.f, 0.f, 0.f, 0.f};
#pragma unroll
        for (int ni = 0; ni < 8; ++ni) {
#pragma unroll
            for (int r = 0; r < 4; ++r) {
                float t = (mi ? acc1[ni][r] : acc0[ni][r]) + b1v[ni];
                t = t > 0.f ? t : 0.f;
                p0[r] += t * w2v[ni].x;
                p1[r] += t * w2v[ni].y;
            }
        }
#pragma unroll
        for (int r = 0; r < 4; ++r) {
#pragma unroll
            for (int m = 1; m < 16; m <<= 1) {
                p0[r] += __shfl_xor(p0[r], m, 64);
                p1[r] += __shfl_xor(p1[r], m, 64);
            }
        }
        if (c < 2) {
            int rowb = base_m + mi * 16 + kg * 4;
#pragma unroll
            for (int r = 0; r < 4; ++r) {
                int row = rowb + r;
                if (row < N_NODES)
                    out[(long)row * 2 + c] = (c == 0 ? p0[r] : p1[r]) + bl2[c];
            }
        }
    }
}

// ---------------- launch ----------------

extern "C" void kernel_launch(void* const* d_in, const int* in_sizes, int n_in,
                              void* d_out, int out_size, void* d_ws, size_t ws_size,
                              hipStream_t stream) {
    const float* x   = (const float*)d_in[0];
    const int* esrc  = (const int*)d_in[1];
    const int* edst  = (const int*)d_in[2];
    const float* ew1 = (const float*)d_in[3];
    const float* ew2 = (const float*)d_in[4];
    const float* W1  = (const float*)d_in[5];
    const float* b1  = (const float*)d_in[6];
    const float* W2  = (const float*)d_in[7];
    const float* b2  = (const float*)d_in[8];
    const float* Wl1 = (const float*)d_in[9];
    const float* bl1 = (const float*)d_in[10];
    const float* Wl2 = (const float*)d_in[11];
    const float* bl2 = (const float*)d_in[12];
    float* out = (float*)d_out;

    char* p = (char*)d_ws;
    float* A        = (float*)p;           p += (size_t)N_NODES * D * 4;   // agg (fp32)
    ushort* h1h     = (ushort*)p;          p += (size_t)N_NODES * D * 2;   // h1/h2 hi (aliased)
    ushort* h1l     = (ushort*)p;          p += (size_t)N_NODES * D * 2;   // h1/h2 lo
    float* deg_inv  = (float*)p;           p += (size_t)N_NODES * 4;
    int* deg        = (int*)p;             p += (size_t)N_NODES * 4;
    int* row_ptr    = (int*)p;             p += (size_t)(N_NODES + 16) * 4;
    int* blocksums  = (int*)p;             p += 128 * 4;
    int* blockoff   = (int*)p;             p += 128 * 4;
    uint2* packed   = (uint2*)p;           p += (size_t)N_EDGES * 8;
    ushort* xbf     = (ushort*)p;          p += (size_t)N_NODES * D * 2;
    ushort* W1th    = (ushort*)p;          p += 2 * D * D * 2;
    ushort* W1tl    = (ushort*)p;          p += 2 * D * D * 2;
    ushort* W2th    = (ushort*)p;          p += 2 * D * D * 2;
    ushort* W2tl    = (ushort*)p;          p += 2 * D * D * 2;
    ushort* Wl1th   = (ushort*)p;          p += D * D * 2;
    ushort* Wl1tl   = (ushort*)p;          p += D * D * 2;
    int* rank       = (int*)xbf;           // rank dead before cvt writes xbf

    hipMemsetAsync(deg, 0, (size_t)N_NODES * 4, stream);

    int egrid = (N_EDGES + 255) / 256;
    hist_kernel<<<egrid, 256, 0, stream>>>(edst, deg, rank);
    scan1_kernel<<<SCAN_NBLK, SCAN_THR, 0, stream>>>(deg, blocksums);
    scan2_kernel<<<1, 128, 0, stream>>>(blocksums, blockoff, row_ptr);
    scan3_kernel<<<SCAN_NBLK, SCAN_THR, 0, stream>>>(deg, blockoff, row_ptr, deg_inv);
    scatter_kernel<<<egrid, 256, 0, stream>>>(esrc, edst, ew1, ew2, rank, row_ptr,
                                              deg_inv, packed);
    cvt_bf16_kernel<<<(N_NODES * D) / (256 * 8), 256, 0, stream>>>(x, xbf);
    wtile_kernel<<<(2 * D * D + 255) / 256, 256, 0, stream>>>(W1, W1th, W1tl, 2 * D * D);
    wtile_kernel<<<(2 * D * D + 255) / 256, 256, 0, stream>>>(W2, W2th, W2tl, 2 * D * D);
    wtile_kernel<<<(D * D + 255) / 256, 256, 0, stream>>>(Wl1, Wl1th, Wl1tl, D * D);

    int ggrid = (N_NODES + 127) / 128;   // 782

    // layer 1
    spmm_kernel<<<N_NODES / 4, 256, 0, stream>>>(xbf, packed, row_ptr, A, 0);
    gemm_mfma_kernel<false><<<ggrid, 256, 0, stream>>>(x, nullptr, nullptr, A,
                                                       W1th, W1tl, b1, h1h, h1l);
    // layer 2 (h2 overwrites h1 in place: each wave reads only its own 32 rows first)
    spmm_kernel<<<N_NODES / 4, 256, 0, stream>>>(h1h, packed, row_ptr, A, 1);
    gemm_mfma_kernel<true><<<ggrid, 256, 0, stream>>>(nullptr, h1h, h1l, A,
                                                      W2th, W2tl, b2, h1h, h1l);
    // classifier
    cls_mfma_kernel<<<ggrid, 256, 0, stream>>>(h1h, h1l, Wl1th, Wl1tl, bl1, Wl2, bl2, out);
}

// Round 7
// 350.755 us; speedup vs baseline: 2.9798x; 1.1546x over previous
//
#include <hip/hip_runtime.h>
#include <hip/hip_fp16.h>

#define N_NODES 100000
#define N_EDGES 1600000
#define D 128

typedef __attribute__((ext_vector_type(8))) _Float16 f16x8;
typedef __attribute__((ext_vector_type(4))) float f32x4;

__device__ __forceinline__ float h2f(ushort u) {
    __half_raw r; r.x = u;
    return __half2float(__half(r));
}
__device__ __forceinline__ ushort f2h(float f) {
    __half_raw r = __half_raw(__float2half(f));
    return r.x;
}

// ---------------- CSR build ----------------

__global__ __launch_bounds__(256) void hist_kernel(const int* __restrict__ dst,
                                                   int* __restrict__ deg,
                                                   int* __restrict__ rank) {
    int i = blockIdx.x * 256 + threadIdx.x;
    if (i < N_EDGES) rank[i] = atomicAdd(&deg[dst[i]], 1);
}

#define SCAN_BLK 1024
#define SCAN_THR 256
#define SCAN_NBLK ((N_NODES + SCAN_BLK - 1) / SCAN_BLK)   // 98

__global__ __launch_bounds__(SCAN_THR) void scan1_kernel(const int* __restrict__ deg,
                                                         int* __restrict__ blocksums) {
    __shared__ int sums[SCAN_THR];
    int tid = threadIdx.x;
    int base = blockIdx.x * SCAN_BLK + tid * 4;
    int s = 0;
    if (base + 3 < N_NODES) {
        const int4 v = *reinterpret_cast<const int4*>(&deg[base]);
        s = v.x + v.y + v.z + v.w;
    } else {
#pragma unroll
        for (int i = 0; i < 4; ++i)
            if (base + i < N_NODES) s += deg[base + i];
    }
    sums[tid] = s;
    __syncthreads();
#pragma unroll
    for (int off = SCAN_THR / 2; off > 0; off >>= 1) {
        if (tid < off) sums[tid] += sums[tid + off];
        __syncthreads();
    }
    if (tid == 0) blocksums[blockIdx.x] = sums[0];
}

__global__ __launch_bounds__(128) void scan2_kernel(const int* __restrict__ blocksums,
                                                    int* __restrict__ blockoff,
                                                    int* __restrict__ row_ptr) {
    __shared__ int s[128];
    int tid = threadIdx.x;
    int v = (tid < SCAN_NBLK) ? blocksums[tid] : 0;
    s[tid] = v;
    __syncthreads();
    for (int off = 1; off < 128; off <<= 1) {
        int t = (tid >= off) ? s[tid - off] : 0;
        __syncthreads();
        s[tid] += t;
        __syncthreads();
    }
    if (tid < SCAN_NBLK) blockoff[tid] = s[tid] - v;   // exclusive
    if (tid == 127) row_ptr[N_NODES] = s[127];         // grand total
}

__global__ __launch_bounds__(SCAN_THR) void scan3_kernel(const int* __restrict__ deg,
                                                         const int* __restrict__ blockoff,
                                                         int* __restrict__ row_ptr,
                                                         float* __restrict__ deg_inv) {
    __shared__ int tsum[SCAN_THR];
    int tid = threadIdx.x;
    int base = blockIdx.x * SCAN_BLK + tid * 4;
    int d[4];
#pragma unroll
    for (int i = 0; i < 4; ++i)
        d[i] = (base + i < N_NODES) ? deg[base + i] : 0;
    int s = d[0] + d[1] + d[2] + d[3];
    tsum[tid] = s;
    __syncthreads();
    for (int off = 1; off < SCAN_THR; off <<= 1) {
        int t = (tid >= off) ? tsum[tid - off] : 0;
        __syncthreads();
        tsum[tid] += t;
        __syncthreads();
    }
    int run = blockoff[blockIdx.x] + tsum[tid] - s;    // exclusive start
#pragma unroll
    for (int i = 0; i < 4; ++i) {
        int idx = base + i;
        if (idx < N_NODES) {
            row_ptr[idx] = run;
            deg_inv[idx] = d[i] > 0 ? 1.0f / (float)d[i] : 0.0f;
            run += d[i];
        }
    }
}

// atomic-free scatter: one random 8B write per edge.
// Weights pre-scaled by deg_inv[dst] (mean folded in), stored as fp16 pair.
__global__ __launch_bounds__(256) void scatter_kernel(const int* __restrict__ src,
                                                      const int* __restrict__ dst,
                                                      const float* __restrict__ w1,
                                                      const float* __restrict__ w2,
                                                      const int* __restrict__ rank,
                                                      const int* __restrict__ row_ptr,
                                                      const float* __restrict__ deg_inv,
                                                      uint2* __restrict__ packed) {
    int i = blockIdx.x * 256 + threadIdx.x;
    if (i < N_EDGES) {
        int d = dst[i];
        int p = row_ptr[d] + rank[i];
        float di = deg_inv[d];
        uint2 e;
        e.x = (unsigned)src[i];
        e.y = (unsigned)f2h(w1[i] * di) | ((unsigned)f2h(w2[i] * di) << 16);
        packed[p] = e;
    }
}

// ---------------- fp32 -> fp16 convert (8 elems/thread) ----------------

__global__ __launch_bounds__(256) void cvt_f16_kernel(const float* __restrict__ in,
                                                      ushort* __restrict__ out) {
    long i = ((long)blockIdx.x * 256 + threadIdx.x) * 8;
    const float4 a = *reinterpret_cast<const float4*>(&in[i]);
    const float4 b = *reinterpret_cast<const float4*>(&in[i + 4]);
    ushort4 u0, u1;
    u0.x = f2h(a.x); u0.y = f2h(a.y); u0.z = f2h(a.z); u0.w = f2h(a.w);
    u1.x = f2h(b.x); u1.y = f2h(b.y); u1.z = f2h(b.z); u1.w = f2h(b.w);
    *reinterpret_cast<ushort4*>(&out[i]) = u0;
    *reinterpret_cast<ushort4*>(&out[i + 4]) = u1;
}

// ---------------- W tiling: fragment-ordered fp16 ----------------
// addr(k,n) = ((k>>3)*128 + n)*8 + (k&7)  -> b-frag for (kgroup, n) is 16B contiguous

__global__ __launch_bounds__(256) void wtile_kernel(const float* __restrict__ W,
                                                    ushort* __restrict__ th,
                                                    int total) {
    int i = blockIdx.x * 256 + threadIdx.x;
    if (i < total) {
        int k = i >> 7, n = i & 127;
        int addr = (((k >> 3) << 7) + n) * 8 + (k & 7);
        th[addr] = f2h(W[i]);
    }
}

// ---------------- SpMM: sum of pre-scaled fp16 gathers + leaky-relu ----------------
// wave-per-node; 32 lanes cover a row (ushort4/lane); lane-half = edge parity.
// 8 edges per iteration -> 4 independent gathers in flight.

__global__ __launch_bounds__(256) void spmm_kernel(const ushort* __restrict__ xin,
                                                   const uint2* __restrict__ edges,
                                                   const int* __restrict__ row_ptr,
                                                   ushort* __restrict__ out,
                                                   int widx) {
    int wid = threadIdx.x >> 6;
    int half = (threadIdx.x >> 5) & 1;     // edge parity handled by this lane-half
    int l = threadIdx.x & 31;              // dim group: dims 4l..4l+3
    int n = blockIdx.x * 4 + wid;
    int beg = row_ptr[n], end = row_ptr[n + 1];
    float a0 = 0.f, a1 = 0.f, a2 = 0.f, a3 = 0.f;

    int i = beg;
    for (; i + 7 < end; i += 8) {
        const uint2 e0 = edges[i + half];
        const uint2 e1 = edges[i + 2 + half];
        const uint2 e2 = edges[i + 4 + half];
        const uint2 e3 = edges[i + 6 + half];
        float w0 = h2f((ushort)(widx ? (e0.y >> 16) : (e0.y & 0xFFFFu)));
        float w1 = h2f((ushort)(widx ? (e1.y >> 16) : (e1.y & 0xFFFFu)));
        float w2 = h2f((ushort)(widx ? (e2.y >> 16) : (e2.y & 0xFFFFu)));
        float w3 = h2f((ushort)(widx ? (e3.y >> 16) : (e3.y & 0xFFFFu)));
        const ushort4 u0 = *reinterpret_cast<const ushort4*>(&xin[(long)e0.x * D + l * 4]);
        const ushort4 u1 = *reinterpret_cast<const ushort4*>(&xin[(long)e1.x * D + l * 4]);
        const ushort4 u2 = *reinterpret_cast<const ushort4*>(&xin[(long)e2.x * D + l * 4]);
        const ushort4 u3 = *reinterpret_cast<const ushort4*>(&xin[(long)e3.x * D + l * 4]);
        a0 += w0 * h2f(u0.x) + w1 * h2f(u1.x) + w2 * h2f(u2.x) + w3 * h2f(u3.x);
        a1 += w0 * h2f(u0.y) + w1 * h2f(u1.y) + w2 * h2f(u2.y) + w3 * h2f(u3.y);
        a2 += w0 * h2f(u0.z) + w1 * h2f(u1.z) + w2 * h2f(u2.z) + w3 * h2f(u3.z);
        a3 += w0 * h2f(u0.w) + w1 * h2f(u1.w) + w2 * h2f(u2.w) + w3 * h2f(u3.w);
    }
    for (; i + 1 < end; i += 2) {
        const uint2 e0 = edges[i + half];
        float w0 = h2f((ushort)(widx ? (e0.y >> 16) : (e0.y & 0xFFFFu)));
        const ushort4 u0 = *reinterpret_cast<const ushort4*>(&xin[(long)e0.x * D + l * 4]);
        a0 += w0 * h2f(u0.x);
        a1 += w0 * h2f(u0.y);
        a2 += w0 * h2f(u0.z);
        a3 += w0 * h2f(u0.w);
    }
    if (i < end) {
        // odd tail: both halves load the last edge; half 1 contributes 0
        const uint2 e0 = edges[i];
        float w0 = half ? 0.f : h2f((ushort)(widx ? (e0.y >> 16) : (e0.y & 0xFFFFu)));
        const ushort4 u0 = *reinterpret_cast<const ushort4*>(&xin[(long)e0.x * D + l * 4]);
        a0 += w0 * h2f(u0.x);
        a1 += w0 * h2f(u0.y);
        a2 += w0 * h2f(u0.z);
        a3 += w0 * h2f(u0.w);
    }

    // combine the two edge-parity halves (lane ^ 32)
    a0 += __shfl_xor(a0, 32, 64);
    a1 += __shfl_xor(a1, 32, 64);
    a2 += __shfl_xor(a2, 32, 64);
    a3 += __shfl_xor(a3, 32, 64);

    if (half == 0) {
        a0 = a0 > 0.f ? a0 : 0.01f * a0;
        a1 = a1 > 0.f ? a1 : 0.01f * a1;
        a2 = a2 > 0.f ? a2 : 0.01f * a2;
        a3 = a3 > 0.f ? a3 : 0.01f * a3;
        ushort4 r;
        r.x = f2h(a0); r.y = f2h(a1); r.z = f2h(a2); r.w = f2h(a3);
        *reinterpret_cast<ushort4*>(&out[(long)n * D + l * 4]) = r;
    }
}

// ---------------- MFMA fp16 GEMM: out = relu([in1|in2] @ W + b) as fp16 ----------
// LDS-free: per-wave 32 rows; A-frags direct from global; B-frags from pre-tiled W.

__global__ __launch_bounds__(256) void gemm_mfma_kernel(
        const ushort* __restrict__ in1,
        const ushort* __restrict__ in2,
        const ushort* __restrict__ Wt,
        const float* __restrict__ bias,
        ushort* __restrict__ outp) {
    int tid = threadIdx.x;
    int w = tid >> 6, l = tid & 63;
    int c = l & 15, kg = l >> 4;
    int base_m = blockIdx.x * 128 + w * 32;
    int r0 = base_m + c;       if (r0 >= N_NODES) r0 = N_NODES - 1;
    int r1 = base_m + 16 + c;  if (r1 >= N_NODES) r1 = N_NODES - 1;

    f32x4 acc0[8], acc1[8];
#pragma unroll
    for (int ni = 0; ni < 8; ++ni) { acc0[ni] = (f32x4)0.f; acc1[ni] = (f32x4)0.f; }

    for (int ks = 0; ks < 8; ++ks) {
        int kb = (ks & 3) * 32 + kg * 8;
        const ushort* src = (ks < 4) ? in1 : in2;
        f16x8 a0 = *reinterpret_cast<const f16x8*>(&src[(long)r0 * D + kb]);
        f16x8 a1 = *reinterpret_cast<const f16x8*>(&src[(long)r1 * D + kb]);
        const ushort* wb = &Wt[(size_t)((ks * 4 + kg) * 128) * 8];
#pragma unroll
        for (int ni = 0; ni < 8; ++ni) {
            const f16x8 b = *reinterpret_cast<const f16x8*>(&wb[(ni * 16 + c) * 8]);
            acc0[ni] = __builtin_amdgcn_mfma_f32_16x16x32_f16(a0, b, acc0[ni], 0, 0, 0);
            acc1[ni] = __builtin_amdgcn_mfma_f32_16x16x32_f16(a1, b, acc1[ni], 0, 0, 0);
        }
    }

    float bv[8];
#pragma unroll
    for (int ni = 0; ni < 8; ++ni) bv[ni] = bias[ni * 16 + c];
#pragma unroll
    for (int mi = 0; mi < 2; ++mi) {
        int rowb = base_m + mi * 16 + kg * 4;
#pragma unroll
        for (int r = 0; r < 4; ++r) {
            int row = rowb + r;
            if (row < N_NODES) {
#pragma unroll
                for (int ni = 0; ni < 8; ++ni) {
                    float v = (mi ? acc1[ni][r] : acc0[ni][r]) + bv[ni];
                    v = v > 0.f ? v : 0.f;
                    outp[(long)row * D + ni * 16 + c] = f2h(v);
                }
            }
        }
    }
}

// ---------------- Classifier: out = relu(H @ Wl1 + bl1) @ Wl2 + bl2 ----------------

__global__ __launch_bounds__(256) void cls_mfma_kernel(
        const ushort* __restrict__ H,
        const ushort* __restrict__ Wt,
        const float* __restrict__ bl1, const float* __restrict__ Wl2,
        const float* __restrict__ bl2, float* __restrict__ out) {
    int tid = threadIdx.x;
    int w = tid >> 6, l = tid & 63;
    int c = l & 15, kg = l >> 4;
    int base_m = blockIdx.x * 128 + w * 32;
    int r0 = base_m + c;       if (r0 >= N_NODES) r0 = N_NODES - 1;
    int r1 = base_m + 16 + c;  if (r1 >= N_NODES) r1 = N_NODES - 1;

    f32x4 acc0[8], acc1[8];
#pragma unroll
    for (int ni = 0; ni < 8; ++ni) { acc0[ni] = (f32x4)0.f; acc1[ni] = (f32x4)0.f; }

    for (int ks = 0; ks < 4; ++ks) {
        int kb = ks * 32 + kg * 8;
        f16x8 a0 = *reinterpret_cast<const f16x8*>(&H[(long)r0 * D + kb]);
        f16x8 a1 = *reinterpret_cast<const f16x8*>(&H[(long)r1 * D + kb]);
        const ushort* wb = &Wt[(size_t)((ks * 4 + kg) * 128) * 8];
#pragma unroll
        for (int ni = 0; ni < 8; ++ni) {
            const f16x8 b = *reinterpret_cast<const f16x8*>(&wb[(ni * 16 + c) * 8]);
            acc0[ni] = __builtin_amdgcn_mfma_f32_16x16x32_f16(a0, b, acc0[ni], 0, 0, 0);
            acc1[ni] = __builtin_amdgcn_mfma_f32_16x16x32_f16(a1, b, acc1[ni], 0, 0, 0);
        }
    }

    float b1v[8]; float2 w2v[8];
#pragma unroll
    for (int ni = 0; ni < 8; ++ni) {
        b1v[ni] = bl1[ni * 16 + c];
        w2v[ni] = *reinterpret_cast<const float2*>(&Wl2[(ni * 16 + c) * 2]);
    }
#pragma unroll
    for (int mi = 0; mi < 2; ++mi) {
        float p0[4] = {0.f, 0.f, 0.f, 0.f};
        float p1[4] = {0.f, 0.f, 0.f, 0.f};
#pragma unroll
        for (int ni = 0; ni < 8; ++ni) {
#pragma unroll
            for (int r = 0; r < 4; ++r) {
                float t = (mi ? acc1[ni][r] : acc0[ni][r]) + b1v[ni];
                t = t > 0.f ? t : 0.f;
                p0[r] += t * w2v[ni].x;
                p1[r] += t * w2v[ni].y;
            }
        }
#pragma unroll
        for (int r = 0; r < 4; ++r) {
#pragma unroll
            for (int m = 1; m < 16; m <<= 1) {
                p0[r] += __shfl_xor(p0[r], m, 64);
                p1[r] += __shfl_xor(p1[r], m, 64);
            }
        }
        if (c < 2) {
            int rowb = base_m + mi * 16 + kg * 4;
#pragma unroll
            for (int r = 0; r < 4; ++r) {
                int row = rowb + r;
                if (row < N_NODES)
                    out[(long)row * 2 + c] = (c == 0 ? p0[r] : p1[r]) + bl2[c];
            }
        }
    }
}

// ---------------- launch ----------------

extern "C" void kernel_launch(void* const* d_in, const int* in_sizes, int n_in,
                              void* d_out, int out_size, void* d_ws, size_t ws_size,
                              hipStream_t stream) {
    const float* x   = (const float*)d_in[0];
    const int* esrc  = (const int*)d_in[1];
    const int* edst  = (const int*)d_in[2];
    const float* ew1 = (const float*)d_in[3];
    const float* ew2 = (const float*)d_in[4];
    const float* W1  = (const float*)d_in[5];
    const float* b1  = (const float*)d_in[6];
    const float* W2  = (const float*)d_in[7];
    const float* b2  = (const float*)d_in[8];
    const float* Wl1 = (const float*)d_in[9];
    const float* bl1 = (const float*)d_in[10];
    const float* Wl2 = (const float*)d_in[11];
    const float* bl2 = (const float*)d_in[12];
    float* out = (float*)d_out;

    char* p = (char*)d_ws;
    ushort* Af      = (ushort*)p;          p += (size_t)N_NODES * D * 2;   // agg (fp16)
    ushort* h1f     = (ushort*)p;          p += (size_t)N_NODES * D * 2;   // h1/h2 (fp16, aliased)
    ushort* xf      = (ushort*)p;          p += (size_t)N_NODES * D * 2;   // x (fp16)
    float* deg_inv  = (float*)p;           p += (size_t)N_NODES * 4;
    int* deg        = (int*)p;             p += (size_t)N_NODES * 4;
    int* row_ptr    = (int*)p;             p += (size_t)(N_NODES + 16) * 4;
    int* blocksums  = (int*)p;             p += 128 * 4;
    int* blockoff   = (int*)p;             p += 128 * 4;
    uint2* packed   = (uint2*)p;           p += (size_t)N_EDGES * 8;
    ushort* W1t     = (ushort*)p;          p += 2 * D * D * 2;
    ushort* W2t     = (ushort*)p;          p += 2 * D * D * 2;
    ushort* Wl1t    = (ushort*)p;          p += D * D * 2;
    int* rank       = (int*)xf;            // rank dead before cvt writes xf

    hipMemsetAsync(deg, 0, (size_t)N_NODES * 4, stream);

    int egrid = (N_EDGES + 255) / 256;
    hist_kernel<<<egrid, 256, 0, stream>>>(edst, deg, rank);
    scan1_kernel<<<SCAN_NBLK, SCAN_THR, 0, stream>>>(deg, blocksums);
    scan2_kernel<<<1, 128, 0, stream>>>(blocksums, blockoff, row_ptr);
    scan3_kernel<<<SCAN_NBLK, SCAN_THR, 0, stream>>>(deg, blockoff, row_ptr, deg_inv);
    scatter_kernel<<<egrid, 256, 0, stream>>>(esrc, edst, ew1, ew2, rank, row_ptr,
                                              deg_inv, packed);
    cvt_f16_kernel<<<(N_NODES * D) / (256 * 8), 256, 0, stream>>>(x, xf);
    wtile_kernel<<<(2 * D * D + 255) / 256, 256, 0, stream>>>(W1, W1t, 2 * D * D);
    wtile_kernel<<<(2 * D * D + 255) / 256, 256, 0, stream>>>(W2, W2t, 2 * D * D);
    wtile_kernel<<<(D * D + 255) / 256, 256, 0, stream>>>(Wl1, Wl1t, D * D);

    int ggrid = (N_NODES + 127) / 128;   // 782

    // layer 1
    spmm_kernel<<<N_NODES / 4, 256, 0, stream>>>(xf, packed, row_ptr, Af, 0);
    gemm_mfma_kernel<<<ggrid, 256, 0, stream>>>(xf, Af, W1t, b1, h1f);
    // layer 2 (h2 overwrites h1 in place: each wave reads only its own 32 rows first)
    spmm_kernel<<<N_NODES / 4, 256, 0, stream>>>(h1f, packed, row_ptr, Af, 1);
    gemm_mfma_kernel<<<ggrid, 256, 0, stream>>>(h1f, Af, W2t, b2, h1f);
    // classifier
    cls_mfma_kernel<<<ggrid, 256, 0, stream>>>(h1f, Wl1t, bl1, Wl2, bl2, out);
}